// Round 1
// baseline (1787.612 us; speedup 1.0000x reference)
//
#include <hip/hip_runtime.h>
#include <hip/hip_bf16.h>
#include <math.h>

// ---------------------------------------------------------------------------
// GraphMixer forward: emb -> 3x [LN -> GATv2 -> MLP] -> gated-attn pool -> cls
// Round 1: correctness-first fp32 implementation.
//   - tiled fp32 GEMM (BM=128,BN=64,BK=16, 8x4 microtile, 256 thr)
//   - device-built CSR (incoming edges per node) for segment softmax
//   - wave-per-node GAT aggregation, layernorm, pooling
// ---------------------------------------------------------------------------

#define D 128
#define NBLK 3

static __device__ __forceinline__ float wred_sum(float v) {
#pragma unroll
    for (int m = 1; m < 64; m <<= 1) v += __shfl_xor(v, m, 64);
    return v;
}

// ---------------- CSR build ----------------
__global__ void zero_k(int* deg, int* fill, float* red, int n) {
    int i = blockIdx.x * blockDim.x + threadIdx.x;
    if (i < n) { deg[i] = 0; fill[i] = 0; }
    if (i < 132) red[i] = 0.f;
}

__global__ void hist_k(const int* __restrict__ dst, int* __restrict__ deg, int E) {
    int e = blockIdx.x * blockDim.x + threadIdx.x;
    if (e < E) atomicAdd(&deg[dst[e]], 1);
}

__global__ __launch_bounds__(1024) void scan_k(const int* __restrict__ deg,
                                               int* __restrict__ rowptr, int n) {
    __shared__ int tmp[1024];
    int carry = 0;
    if (threadIdx.x == 0) rowptr[0] = 0;
    for (int base = 0; base < n; base += 1024) {
        int i = base + threadIdx.x;
        int v = (i < n) ? deg[i] : 0;
        tmp[threadIdx.x] = v;
        __syncthreads();
#pragma unroll
        for (int off = 1; off < 1024; off <<= 1) {
            int t = (threadIdx.x >= off) ? tmp[threadIdx.x - off] : 0;
            __syncthreads();
            tmp[threadIdx.x] += t;
            __syncthreads();
        }
        if (i < n) rowptr[i + 1] = carry + tmp[threadIdx.x];
        int total = tmp[1023];
        __syncthreads();
        carry += total;
    }
}

__global__ void scatter_k(const int* __restrict__ src, const int* __restrict__ dst,
                          const int* __restrict__ rowptr, int* __restrict__ fill,
                          int* __restrict__ esrc, int E) {
    int e = blockIdx.x * blockDim.x + threadIdx.x;
    if (e < E) {
        int d = dst[e];
        int pos = rowptr[d] + atomicAdd(&fill[d], 1);
        esrc[pos] = src[e];
    }
}

// ---------------- GEMM: C = act(A@B [+bias]) [+= existing C] ----------------
// A: [N,K] row-major, B: [K,M] row-major, M % 64 == 0, K % 16 == 0
#define BM 128
#define BN 64
#define BK 16

template <int ACT, bool HAS_BIAS, bool ACC>
__global__ __launch_bounds__(256) void gemm_k(const float* __restrict__ A,
                                              const float* __restrict__ B,
                                              const float* __restrict__ bias,
                                              float* __restrict__ C,
                                              int N, int K, int M) {
    __shared__ float As[BK][BM];
    __shared__ float Bs[BK][BN + 4];
    const int t = threadIdx.x;
    const int row0 = blockIdx.x * BM;
    const int col0 = blockIdx.y * BN;
    const int ar = t >> 2;          // 0..63
    const int ak = (t & 3) * 4;     // 0,4,8,12
    const int bk = t >> 4;          // 0..15
    const int bn = (t & 15) * 4;    // 0..60
    const int tx = t & 15;          // col group
    const int ty = t >> 4;          // row group

    float acc[8][4];
#pragma unroll
    for (int i = 0; i < 8; ++i)
#pragma unroll
        for (int j = 0; j < 4; ++j) acc[i][j] = 0.f;

    for (int k0 = 0; k0 < K; k0 += BK) {
        const int r0 = row0 + ar, r1 = row0 + ar + 64;
        float4 a0 = make_float4(0.f, 0.f, 0.f, 0.f), a1 = a0;
        if (r0 < N) a0 = *(const float4*)(A + (size_t)r0 * K + k0 + ak);
        if (r1 < N) a1 = *(const float4*)(A + (size_t)r1 * K + k0 + ak);
        const float4 bv = *(const float4*)(B + (size_t)(k0 + bk) * M + col0 + bn);
        __syncthreads();
        As[ak + 0][ar] = a0.x; As[ak + 1][ar] = a0.y;
        As[ak + 2][ar] = a0.z; As[ak + 3][ar] = a0.w;
        As[ak + 0][ar + 64] = a1.x; As[ak + 1][ar + 64] = a1.y;
        As[ak + 2][ar + 64] = a1.z; As[ak + 3][ar + 64] = a1.w;
        *(float4*)&Bs[bk][bn] = bv;
        __syncthreads();
#pragma unroll
        for (int k = 0; k < BK; ++k) {
            const float4 aa0 = *(const float4*)&As[k][ty * 8];
            const float4 aa1 = *(const float4*)&As[k][ty * 8 + 4];
            const float4 bb = *(const float4*)&Bs[k][tx * 4];
            const float av[8] = {aa0.x, aa0.y, aa0.z, aa0.w, aa1.x, aa1.y, aa1.z, aa1.w};
            const float bw[4] = {bb.x, bb.y, bb.z, bb.w};
#pragma unroll
            for (int i = 0; i < 8; ++i)
#pragma unroll
                for (int j = 0; j < 4; ++j)
                    acc[i][j] = fmaf(av[i], bw[j], acc[i][j]);
        }
    }

    float bvals[4] = {0.f, 0.f, 0.f, 0.f};
    if (HAS_BIAS) {
        const float4 b4 = *(const float4*)(bias + col0 + tx * 4);
        bvals[0] = b4.x; bvals[1] = b4.y; bvals[2] = b4.z; bvals[3] = b4.w;
    }
#pragma unroll
    for (int i = 0; i < 8; ++i) {
        const int r = row0 + ty * 8 + i;
        if (r >= N) continue;
        float v[4];
#pragma unroll
        for (int j = 0; j < 4; ++j) {
            float x = acc[i][j] + bvals[j];
            if (ACT == 1) x = fmaxf(x, 0.f);                              // relu
            else if (ACT == 2) x = 0.5f * x * (1.f + erff(x * 0.70710678118654752f)); // gelu exact
            else if (ACT == 3) x = tanhf(x);
            else if (ACT == 4) x = 1.f / (1.f + expf(-x));                // sigmoid
            v[j] = x;
        }
        float* cp = C + (size_t)r * M + col0 + tx * 4;
        if (ACC) {
            const float4 o = *(const float4*)cp;
            v[0] += o.x; v[1] += o.y; v[2] += o.z; v[3] += o.w;
        }
        float4 st = make_float4(v[0], v[1], v[2], v[3]);
        *(float4*)cp = st;
    }
}

// ---------------- LayerNorm (wave per node) ----------------
__global__ __launch_bounds__(256) void ln_k(const float* __restrict__ H,
                                            const float* __restrict__ g,
                                            const float* __restrict__ b,
                                            float* __restrict__ HN, int n) {
    const int lane = threadIdx.x & 63;
    const int node = blockIdx.x * 4 + (threadIdx.x >> 6);
    if (node >= n) return;
    const float x0 = H[(size_t)node * D + lane];
    const float x1 = H[(size_t)node * D + 64 + lane];
    const float mu = wred_sum(x0 + x1) * (1.f / 128.f);
    const float d0 = x0 - mu, d1 = x1 - mu;
    const float var = wred_sum(d0 * d0 + d1 * d1) * (1.f / 128.f);
    const float rs = rsqrtf(var + 1e-5f);
    HN[(size_t)node * D + lane]      = d0 * rs * g[lane] + b[lane];
    HN[(size_t)node * D + 64 + lane] = d1 * rs * g[64 + lane] + b[64 + lane];
}

// ---------------- GATv2 segment softmax + aggregate (wave per node) --------
__global__ __launch_bounds__(256) void gat_k(const float* __restrict__ XL,
                                             const float* __restrict__ XR,
                                             const float* __restrict__ att,
                                             const float* __restrict__ gbias,
                                             const int* __restrict__ rowptr,
                                             const int* __restrict__ esrc,
                                             float* __restrict__ scores,
                                             float* __restrict__ H, int n) {
    const int lane = threadIdx.x & 63;
    const int node = blockIdx.x * 4 + (threadIdx.x >> 6);
    if (node >= n) return;
    const float att0 = att[lane], att1 = att[64 + lane];
    const float xr0 = XR[(size_t)node * D + lane];
    const float xr1 = XR[(size_t)node * D + 64 + lane];
    const float xs0 = XL[(size_t)node * D + lane];
    const float xs1 = XL[(size_t)node * D + 64 + lane];
    const int p0 = rowptr[node], p1 = rowptr[node + 1];

    // self-loop score
    float c0 = xs0 + xr0; c0 = (c0 > 0.f) ? c0 : 0.2f * c0;
    float c1 = xs1 + xr1; c1 = (c1 > 0.f) ? c1 : 0.2f * c1;
    const float sself = wred_sum(att0 * c0 + att1 * c1);
    float smax = sself;

    for (int p = p0; p < p1; ++p) {
        const int s = esrc[p];
        const float x0 = XL[(size_t)s * D + lane];
        const float x1 = XL[(size_t)s * D + 64 + lane];
        float e0 = x0 + xr0; e0 = (e0 > 0.f) ? e0 : 0.2f * e0;
        float e1 = x1 + xr1; e1 = (e1 > 0.f) ? e1 : 0.2f * e1;
        const float sc = wred_sum(att0 * e0 + att1 * e1);
        if (lane == 0) scores[p] = sc;
        smax = fmaxf(smax, sc);
    }

    float ex = expf(sself - smax);
    float denom = ex;
    float a0 = ex * xs0, a1 = ex * xs1;
    for (int p = p0; p < p1; ++p) {
        const int s = esrc[p];
        const float sc = scores[p];
        const float e2 = expf(sc - smax);
        denom += e2;
        a0 = fmaf(e2, XL[(size_t)s * D + lane], a0);
        a1 = fmaf(e2, XL[(size_t)s * D + 64 + lane], a1);
    }
    const float inv = 1.f / denom;
    H[(size_t)node * D + lane]      += a0 * inv + gbias[lane];
    H[(size_t)node * D + 64 + lane] += a1 * inv + gbias[64 + lane];
}

// ---------------- pooling ----------------
__global__ __launch_bounds__(256) void poolA_k(const float* __restrict__ a,
                                               const float* __restrict__ b,
                                               const float* __restrict__ Wc,
                                               const float* __restrict__ bc,
                                               float* __restrict__ A, int n) {
    const int lane = threadIdx.x & 63;
    const int node = blockIdx.x * 4 + (threadIdx.x >> 6);
    if (node >= n) return;
    const size_t o = (size_t)node * D;
    const float v = wred_sum(a[o + lane] * b[o + lane] * Wc[lane] +
                             a[o + 64 + lane] * b[o + 64 + lane] * Wc[64 + lane]);
    if (lane == 0) A[node] = v + bc[0];
}

__global__ __launch_bounds__(1024) void maxA_k(const float* __restrict__ A,
                                               float* __restrict__ red, int n) {
    __shared__ float sm[1024];
    float m = -3.4e38f;
    for (int i = threadIdx.x; i < n; i += 1024) m = fmaxf(m, A[i]);
    sm[threadIdx.x] = m;
    __syncthreads();
    for (int s = 512; s > 0; s >>= 1) {
        if (threadIdx.x < s) sm[threadIdx.x] = fmaxf(sm[threadIdx.x], sm[threadIdx.x + s]);
        __syncthreads();
    }
    if (threadIdx.x == 0) red[129] = sm[0];
}

__global__ __launch_bounds__(256) void wsum_k(const float* __restrict__ A,
                                              const float* __restrict__ H,
                                              float* __restrict__ red, int n) {
    const int lane = threadIdx.x & 63;
    const int gw = blockIdx.x * 4 + (threadIdx.x >> 6);
    const int nw = gridDim.x * 4;
    const float maxA = red[129];
    float a0 = 0.f, a1 = 0.f, dn = 0.f;
    for (int node = gw; node < n; node += nw) {
        const float w = expf(A[node] - maxA);
        dn += w;
        a0 = fmaf(w, H[(size_t)node * D + lane], a0);
        a1 = fmaf(w, H[(size_t)node * D + 64 + lane], a1);
    }
    atomicAdd(&red[lane], a0);
    atomicAdd(&red[64 + lane], a1);
    if (lane == 0) atomicAdd(&red[128], dn);
}

__global__ __launch_bounds__(128) void final_k(const float* __restrict__ red,
                                               const float* __restrict__ rho_W,
                                               const float* __restrict__ rho_b,
                                               const float* __restrict__ cls_W,
                                               const float* __restrict__ cls_b,
                                               float* __restrict__ out) {
    __shared__ float hp[128];
    __shared__ float hr[128];
    __shared__ float lg[4];
    const int t = threadIdx.x;
    hp[t] = red[t] / red[128];
    __syncthreads();
    float s = rho_b[t];
    for (int k = 0; k < 128; ++k) s = fmaf(hp[k], rho_W[k * 128 + t], s);
    hr[t] = fmaxf(s, 0.f);
    __syncthreads();
    if (t < 4) {
        float l = cls_b[t];
        for (int k = 0; k < 128; ++k) l = fmaf(hr[k], cls_W[k * 4 + t], l);
        lg[t] = l;
    }
    __syncthreads();
    if (t == 0) {
        float hz[4], S[4];
        for (int c = 0; c < 4; ++c) hz[c] = 1.f / (1.f + expf(-lg[c]));
        S[0] = 1.f - hz[0];
        for (int c = 1; c < 4; ++c) S[c] = S[c - 1] * (1.f - hz[c]);
        int am = 0; float bm = lg[0];
        for (int c = 1; c < 4; ++c) if (lg[c] > bm) { bm = lg[c]; am = c; }
        out[0] = hz[0]; out[1] = hz[1]; out[2] = hz[2]; out[3] = hz[3];
        out[4] = S[0];  out[5] = S[1];  out[6] = S[2];  out[7] = S[3];
        out[8] = (float)am;
        out[9] = lg[0]; out[10] = lg[1]; out[11] = lg[2]; out[12] = lg[3];
    }
}

// ---------------------------------------------------------------------------
static inline int cdiv(int a, int b) { return (a + b - 1) / b; }

extern "C" void kernel_launch(void* const* d_in, const int* in_sizes, int n_in,
                              void* d_out, int out_size, void* d_ws, size_t ws_size,
                              hipStream_t stream) {
    const float* x      = (const float*)d_in[0];
    const int*   ei     = (const int*)d_in[1];
    const float* emb_W  = (const float*)d_in[2];
    const float* emb_b  = (const float*)d_in[3];
    const float* ln1_g  = (const float*)d_in[4];
    const float* ln1_b  = (const float*)d_in[5];
    const float* gat_Wl = (const float*)d_in[6];
    const float* gat_bl = (const float*)d_in[7];
    const float* gat_Wr = (const float*)d_in[8];
    const float* gat_br = (const float*)d_in[9];
    const float* gat_att  = (const float*)d_in[10];
    const float* gat_bias = (const float*)d_in[11];
    const float* mlp_w1[NBLK] = {(const float*)d_in[12], (const float*)d_in[14], (const float*)d_in[16]};
    const float* mlp_w2[NBLK] = {(const float*)d_in[13], (const float*)d_in[15], (const float*)d_in[17]};
    const float* attn_Wa = (const float*)d_in[18];
    const float* attn_ba = (const float*)d_in[19];
    const float* attn_Wb = (const float*)d_in[20];
    const float* attn_bb = (const float*)d_in[21];
    const float* attn_Wc = (const float*)d_in[22];
    const float* attn_bc = (const float*)d_in[23];
    const float* rho_W   = (const float*)d_in[24];
    const float* rho_b   = (const float*)d_in[25];
    const float* cls_W   = (const float*)d_in[26];
    const float* cls_b   = (const float*)d_in[27];
    float* out = (float*)d_out;

    const int N = in_sizes[0] / 512;   // 50000
    const int E = in_sizes[1] / 2;     // 800000
    const int* src = ei;
    const int* dst = ei + E;

    // workspace layout (floats unless noted)
    char* base = (char*)d_ws;
    float* H      = (float*)base;                         // N*128
    float* HN     = H + (size_t)N * D;                    // N*128
    float* U      = HN + (size_t)N * D;                   // N*384 (XL|XR / T / bufA|bufB)
    float* scores = U + (size_t)N * 384;                  // E
    float* Avec   = scores + E;                           // N
    float* red    = Avec + N;                             // 132
    int*   esrc   = (int*)(red + 132);                    // E
    int*   deg    = esrc + E;                             // N
    int*   rowptr = deg + N;                              // N+1
    int*   fill   = rowptr + N + 1;                       // N

    float* XL = U;
    float* XR = U + (size_t)N * D;
    float* T  = U;
    float* bufA = U;
    float* bufB = U + (size_t)N * D;

    // ---- CSR build ----
    zero_k<<<cdiv(N, 256), 256, 0, stream>>>(deg, fill, red, N);
    hist_k<<<cdiv(E, 256), 256, 0, stream>>>(dst, deg, E);
    scan_k<<<1, 1024, 0, stream>>>(deg, rowptr, N);
    scatter_k<<<cdiv(E, 256), 256, 0, stream>>>(src, dst, rowptr, fill, esrc, E);

    // ---- embedding: H = relu(x @ emb_W + emb_b) ----
    {
        dim3 g(cdiv(N, BM), D / BN);
        gemm_k<1, true, false><<<g, 256, 0, stream>>>(x, emb_W, emb_b, H, N, 512, D);
    }

    // ---- 3 blocks ----
    for (int i = 0; i < NBLK; ++i) {
        ln_k<<<cdiv(N, 4), 256, 0, stream>>>(H, ln1_g + i * D, ln1_b + i * D, HN, N);
        {
            dim3 g(cdiv(N, BM), D / BN);
            gemm_k<0, true, false><<<g, 256, 0, stream>>>(HN, gat_Wl + (size_t)i * D * D,
                                                          gat_bl + i * D, XL, N, D, D);
            gemm_k<0, true, false><<<g, 256, 0, stream>>>(HN, gat_Wr + (size_t)i * D * D,
                                                          gat_br + i * D, XR, N, D, D);
        }
        gat_k<<<cdiv(N, 4), 256, 0, stream>>>(XL, XR, gat_att + i * D, gat_bias + i * D,
                                              rowptr, esrc, scores, H, N);
        const int h = D * (i + 1);
        {
            dim3 g1(cdiv(N, BM), h / BN);
            gemm_k<2, false, false><<<g1, 256, 0, stream>>>(H, mlp_w1[i], nullptr, T, N, D, h);
            dim3 g2(cdiv(N, BM), D / BN);
            gemm_k<0, false, true><<<g2, 256, 0, stream>>>(T, mlp_w2[i], nullptr, H, N, h, D);
        }
    }

    // ---- gated attention pooling ----
    {
        dim3 g(cdiv(N, BM), D / BN);
        gemm_k<3, true, false><<<g, 256, 0, stream>>>(H, attn_Wa, attn_ba, bufA, N, D, D);
        gemm_k<4, true, false><<<g, 256, 0, stream>>>(H, attn_Wb, attn_bb, bufB, N, D, D);
    }
    poolA_k<<<cdiv(N, 4), 256, 0, stream>>>(bufA, bufB, attn_Wc, attn_bc, Avec, N);
    maxA_k<<<1, 1024, 0, stream>>>(Avec, red, N);
    wsum_k<<<120, 256, 0, stream>>>(Avec, H, red, N);
    final_k<<<1, 128, 0, stream>>>(red, rho_W, rho_b, cls_W, cls_b, out);
}

// Round 2
// 1042.133 us; speedup vs baseline: 1.7153x; 1.7153x over previous
//
#include <hip/hip_runtime.h>
#include <math.h>

// ---------------------------------------------------------------------------
// GraphMixer forward, round 2: bf16 MFMA GEMMs + single-pass online-softmax GAT
//   - mgemm_k: BM=128,BN=64,BK=32, 4 waves (2x2), mfma_f32_16x16x32_bf16,
//     global_load_lds(16B) staging, k-chunked LDS layout (conflict-free b128)
//   - weights transposed+cast to bf16 [M][K] on device (one fused kernel)
//   - gat_k: one pass over edges, bf16 XL/XR gathers (256B/edge), online softmax
//   - fp32 residual stream H, bf16 shadow Hb for GEMM inputs
// ---------------------------------------------------------------------------

#define D 128
#define NBLK 3

typedef __attribute__((ext_vector_type(8))) short bf16x8;
typedef __attribute__((ext_vector_type(4))) float f32x4;

static __device__ __forceinline__ float wred_sum(float v) {
#pragma unroll
    for (int m = 1; m < 64; m <<= 1) v += __shfl_xor(v, m, 64);
    return v;
}

static __device__ __forceinline__ float bf2f(unsigned short u) {
    union { unsigned i; float f; } c; c.i = ((unsigned)u) << 16; return c.f;
}
static __device__ __forceinline__ unsigned short f2bf(float f) {
    union { float f; unsigned i; } c; c.f = f;
    unsigned r = c.i + 0x7fff + ((c.i >> 16) & 1);
    return (unsigned short)(r >> 16);
}

static __device__ __forceinline__ void gl16(const unsigned short* g, unsigned short* l) {
    __builtin_amdgcn_global_load_lds((const __attribute__((address_space(1))) void*)g,
                                     (__attribute__((address_space(3))) void*)l, 16, 0, 0);
}

// ---------------- CSR build ----------------
__global__ void zero_k(int* deg, int* fill, float* red, int n) {
    int i = blockIdx.x * blockDim.x + threadIdx.x;
    if (i < n) { deg[i] = 0; fill[i] = 0; }
    if (i < 132) red[i] = 0.f;
}

__global__ void hist_k(const int* __restrict__ dst, int* __restrict__ deg, int E) {
    int e = blockIdx.x * blockDim.x + threadIdx.x;
    if (e < E) atomicAdd(&deg[dst[e]], 1);
}

__global__ __launch_bounds__(256) void blockscan_k(const int* __restrict__ deg,
                                                   int* __restrict__ rowptr,
                                                   int* __restrict__ bsum, int n) {
    __shared__ int tmp[256];
    const int tid = threadIdx.x;
    const int i = blockIdx.x * 256 + tid;
    int v = (i < n) ? deg[i] : 0;
    tmp[tid] = v;
    __syncthreads();
#pragma unroll
    for (int off = 1; off < 256; off <<= 1) {
        int t = (tid >= off) ? tmp[tid - off] : 0;
        __syncthreads();
        tmp[tid] += t;
        __syncthreads();
    }
    if (i < n) rowptr[i + 1] = tmp[tid];
    if (tid == 255) bsum[blockIdx.x] = tmp[255];
}

__global__ __launch_bounds__(256) void scansums_k(int* __restrict__ bsum, int nb) {
    __shared__ int tmp[256];
    const int tid = threadIdx.x;
    int v = (tid < nb) ? bsum[tid] : 0;
    tmp[tid] = v;
    __syncthreads();
#pragma unroll
    for (int off = 1; off < 256; off <<= 1) {
        int t = (tid >= off) ? tmp[tid - off] : 0;
        __syncthreads();
        tmp[tid] += t;
        __syncthreads();
    }
    if (tid < nb) bsum[tid] = tmp[tid];
}

__global__ __launch_bounds__(256) void addoff_k(int* __restrict__ rowptr,
                                                const int* __restrict__ bsum, int n) {
    int i = blockIdx.x * 256 + threadIdx.x;
    if (i == 0) rowptr[0] = 0;
    if (i < n && blockIdx.x > 0) rowptr[i + 1] += bsum[blockIdx.x - 1];
}

__global__ void scatter_k(const int* __restrict__ src, const int* __restrict__ dst,
                          const int* __restrict__ rowptr, int* __restrict__ fill,
                          int* __restrict__ esrc, int E) {
    int e = blockIdx.x * blockDim.x + threadIdx.x;
    if (e < E) {
        int d = dst[e];
        int pos = rowptr[d] + atomicAdd(&fill[d], 1);
        esrc[pos] = src[e];
    }
}

// ---------------- casts / weight prep ----------------
__global__ void xcast_k(const float* __restrict__ x, unsigned short* __restrict__ xb,
                        long n4) {
    long i = (long)blockIdx.x * blockDim.x + threadIdx.x;
    if (i >= n4) return;
    float4 v = ((const float4*)x)[i];
    ushort4 o;
    o.x = f2bf(v.x); o.y = f2bf(v.y); o.z = f2bf(v.z); o.w = f2bf(v.w);
    ((ushort4*)xb)[i] = o;
}

struct WDesc { const float* s; unsigned short* d; int K; int M; };
struct WPack { WDesc w[15]; };

__global__ void wprep_k(WPack p) {
    WDesc d = p.w[blockIdx.y];
    const int total = d.K * d.M;
    for (int i = blockIdx.x * 256 + threadIdx.x; i < total; i += gridDim.x * 256) {
        int m = i % d.M, k = i / d.M;          // src row-major [K][M]
        d.d[(size_t)m * d.K + k] = f2bf(d.s[i]); // dst [M][K]
    }
}

// ---------------- bf16 MFMA GEMM: C = act(A @ BT^T [+bias]) [+C32] ----------
// A: [N][K] bf16, BT: [M][K] bf16 (weights pre-transposed), K%32==0, M%64==0
#define GBM 128
#define GBN 64
#define GBK 32

template <int ACT, bool BIAS, bool ACC, bool W32, bool W16>
__global__ __launch_bounds__(256) void mgemm_k(const unsigned short* __restrict__ A,
                                               const unsigned short* __restrict__ BT,
                                               const float* __restrict__ bias,
                                               float* __restrict__ C32,
                                               unsigned short* __restrict__ C16,
                                               int N, int K, int M) {
    // LDS layout: chunk ci = m16*64 + c8*16 + r16, each chunk = 8 bf16 (16B)
    __shared__ unsigned short Als[GBM * GBK]; // 8 KB
    __shared__ unsigned short Bls[GBN * GBK]; // 4 KB
    const int t = threadIdx.x;
    const int w = t >> 6;            // wave 0..3
    const int l = t & 63;
    const int wm = w >> 1, wn = w & 1;
    const int row0 = blockIdx.x * GBM;
    const int col0 = blockIdx.y * GBN;
    const int c8 = l >> 4, r16 = l & 15;

    int arow0 = row0 + (w * 2 + 0) * 16 + r16; if (arow0 > N - 1) arow0 = N - 1;
    int arow1 = row0 + (w * 2 + 1) * 16 + r16; if (arow1 > N - 1) arow1 = N - 1;
    const int brow = col0 + w * 16 + r16;      // always < M

    f32x4 acc[4][2];
#pragma unroll
    for (int i = 0; i < 4; ++i)
#pragma unroll
        for (int j = 0; j < 2; ++j)
            acc[i][j] = (f32x4){0.f, 0.f, 0.f, 0.f};

    const unsigned short* gA0 = A + (size_t)arow0 * K + c8 * 8;
    const unsigned short* gA1 = A + (size_t)arow1 * K + c8 * 8;
    const unsigned short* gB  = BT + (size_t)brow * K + c8 * 8;

    for (int k0 = 0; k0 < K; k0 += GBK) {
        gl16(gA0 + k0, &Als[(w * 2 + 0) * 512]);  // dest = wave-uniform base + lane*16
        gl16(gA1 + k0, &Als[(w * 2 + 1) * 512]);
        gl16(gB + k0,  &Bls[w * 512]);
        __syncthreads();
        bf16x8 bfr0 = *(const bf16x8*)&Bls[((wn * 2 + 0) * 64 + c8 * 16 + r16) * 8];
        bf16x8 bfr1 = *(const bf16x8*)&Bls[((wn * 2 + 1) * 64 + c8 * 16 + r16) * 8];
#pragma unroll
        for (int tm = 0; tm < 4; ++tm) {
            bf16x8 afr = *(const bf16x8*)&Als[((wm * 4 + tm) * 64 + c8 * 16 + r16) * 8];
            acc[tm][0] = __builtin_amdgcn_mfma_f32_16x16x32_bf16(afr, bfr0, acc[tm][0], 0, 0, 0);
            acc[tm][1] = __builtin_amdgcn_mfma_f32_16x16x32_bf16(afr, bfr1, acc[tm][1], 0, 0, 0);
        }
        __syncthreads();
    }

    // epilogue: C/D layout col=lane&15, row=quad*4+reg
    const int colb = col0 + wn * 32 + (l & 15);
    const int rowb = row0 + wm * 64 + (l >> 4) * 4;
#pragma unroll
    for (int tn = 0; tn < 2; ++tn) {
        const int col = colb + tn * 16;
        float bv = 0.f;
        if (BIAS) bv = bias[col];
#pragma unroll
        for (int tm = 0; tm < 4; ++tm) {
#pragma unroll
            for (int r = 0; r < 4; ++r) {
                const int row = rowb + tm * 16 + r;
                if (row >= N) continue;
                float xv = acc[tm][tn][r] + bv;
                if (ACT == 1) xv = fmaxf(xv, 0.f);
                else if (ACT == 2) xv = 0.5f * xv * (1.f + erff(xv * 0.70710678118654752f));
                else if (ACT == 3) xv = tanhf(xv);
                else if (ACT == 4) xv = 1.f / (1.f + expf(-xv));
                if (ACC) xv += C32[(size_t)row * M + col];
                if (W32) C32[(size_t)row * M + col] = xv;
                if (W16) C16[(size_t)row * M + col] = f2bf(xv);
            }
        }
    }
}

// ---------------- LayerNorm: H fp32 -> HN bf16 (wave per node) --------------
__global__ __launch_bounds__(256) void ln_k(const float* __restrict__ H,
                                            const float* __restrict__ g,
                                            const float* __restrict__ b,
                                            unsigned short* __restrict__ HN, int n) {
    const int l = threadIdx.x & 63;
    const int node = blockIdx.x * 4 + (threadIdx.x >> 6);
    if (node >= n) return;
    const float2 v = *(const float2*)&H[(size_t)node * D + 2 * l];
    const float mu = wred_sum(v.x + v.y) * (1.f / 128.f);
    const float dx = v.x - mu, dy = v.y - mu;
    const float var = wred_sum(dx * dx + dy * dy) * (1.f / 128.f);
    const float rs = rsqrtf(var + 1e-5f);
    ushort2 st;
    st.x = f2bf(dx * rs * g[2 * l] + b[2 * l]);
    st.y = f2bf(dy * rs * g[2 * l + 1] + b[2 * l + 1]);
    *(ushort2*)&HN[(size_t)node * D + 2 * l] = st;
}

// ------- GATv2: single-pass online softmax, bf16 gathers (wave per node) ----
__global__ __launch_bounds__(256) void gat_k(const unsigned short* __restrict__ XL,
                                             const unsigned short* __restrict__ XR,
                                             const float* __restrict__ att,
                                             const float* __restrict__ gbias,
                                             const int* __restrict__ rowptr,
                                             const int* __restrict__ esrc,
                                             float* __restrict__ H,
                                             unsigned short* __restrict__ Hb, int n) {
    const int l = threadIdx.x & 63;
    const int node = blockIdx.x * 4 + (threadIdx.x >> 6);
    if (node >= n) return;
    const float att0 = att[2 * l], att1 = att[2 * l + 1];
    const ushort2 uxr = *(const ushort2*)&XR[(size_t)node * D + 2 * l];
    const ushort2 uxs = *(const ushort2*)&XL[(size_t)node * D + 2 * l];
    const float xr0 = bf2f(uxr.x), xr1 = bf2f(uxr.y);
    const float xs0 = bf2f(uxs.x), xs1 = bf2f(uxs.y);
    const int p0 = rowptr[node], p1 = rowptr[node + 1];

    // self-loop
    float c0 = xs0 + xr0; c0 = (c0 > 0.f) ? c0 : 0.2f * c0;
    float c1 = xs1 + xr1; c1 = (c1 > 0.f) ? c1 : 0.2f * c1;
    float m = wred_sum(att0 * c0 + att1 * c1);
    float dsum = 1.f;
    float a0 = xs0, a1 = xs1;

    for (int p = p0; p < p1; ++p) {
        const int s = esrc[p];
        const ushort2 ux = *(const ushort2*)&XL[(size_t)s * D + 2 * l];
        const float x0 = bf2f(ux.x), x1 = bf2f(ux.y);
        float e0 = x0 + xr0; e0 = (e0 > 0.f) ? e0 : 0.2f * e0;
        float e1 = x1 + xr1; e1 = (e1 > 0.f) ? e1 : 0.2f * e1;
        const float sc = wred_sum(att0 * e0 + att1 * e1);
        if (sc > m) {            // wave-uniform branch
            const float scale = expf(m - sc);
            dsum = dsum * scale + 1.f;
            a0 = a0 * scale + x0;
            a1 = a1 * scale + x1;
            m = sc;
        } else {
            const float wgt = expf(sc - m);
            dsum += wgt;
            a0 = fmaf(wgt, x0, a0);
            a1 = fmaf(wgt, x1, a1);
        }
    }
    const float inv = 1.f / dsum;
    float2 h = *(float2*)&H[(size_t)node * D + 2 * l];
    h.x += a0 * inv + gbias[2 * l];
    h.y += a1 * inv + gbias[2 * l + 1];
    *(float2*)&H[(size_t)node * D + 2 * l] = h;
    ushort2 hb; hb.x = f2bf(h.x); hb.y = f2bf(h.y);
    *(ushort2*)&Hb[(size_t)node * D + 2 * l] = hb;
}

// ---------------- pooling ----------------
__global__ __launch_bounds__(256) void poolA_k(const float* __restrict__ a,
                                               const float* __restrict__ b,
                                               const float* __restrict__ Wc,
                                               const float* __restrict__ bc,
                                               float* __restrict__ A, int n) {
    const int lane = threadIdx.x & 63;
    const int node = blockIdx.x * 4 + (threadIdx.x >> 6);
    if (node >= n) return;
    const size_t o = (size_t)node * D;
    const float v = wred_sum(a[o + lane] * b[o + lane] * Wc[lane] +
                             a[o + 64 + lane] * b[o + 64 + lane] * Wc[64 + lane]);
    if (lane == 0) A[node] = v + bc[0];
}

__global__ __launch_bounds__(1024) void maxA_k(const float* __restrict__ A,
                                               float* __restrict__ red, int n) {
    __shared__ float sm[1024];
    float m = -3.4e38f;
    for (int i = threadIdx.x; i < n; i += 1024) m = fmaxf(m, A[i]);
    sm[threadIdx.x] = m;
    __syncthreads();
    for (int s = 512; s > 0; s >>= 1) {
        if (threadIdx.x < s) sm[threadIdx.x] = fmaxf(sm[threadIdx.x], sm[threadIdx.x + s]);
        __syncthreads();
    }
    if (threadIdx.x == 0) red[129] = sm[0];
}

__global__ __launch_bounds__(256) void wsum_k(const float* __restrict__ A,
                                              const float* __restrict__ H,
                                              float* __restrict__ red, int n) {
    const int lane = threadIdx.x & 63;
    const int gw = blockIdx.x * 4 + (threadIdx.x >> 6);
    const int nw = gridDim.x * 4;
    const float maxA = red[129];
    float a0 = 0.f, a1 = 0.f, dn = 0.f;
    for (int node = gw; node < n; node += nw) {
        const float w = expf(A[node] - maxA);
        dn += w;
        a0 = fmaf(w, H[(size_t)node * D + lane], a0);
        a1 = fmaf(w, H[(size_t)node * D + 64 + lane], a1);
    }
    atomicAdd(&red[lane], a0);
    atomicAdd(&red[64 + lane], a1);
    if (lane == 0) atomicAdd(&red[128], dn);
}

__global__ __launch_bounds__(128) void final_k(const float* __restrict__ red,
                                               const float* __restrict__ rho_W,
                                               const float* __restrict__ rho_b,
                                               const float* __restrict__ cls_W,
                                               const float* __restrict__ cls_b,
                                               float* __restrict__ out) {
    __shared__ float hp[128];
    __shared__ float hr[128];
    __shared__ float lg[4];
    const int t = threadIdx.x;
    hp[t] = red[t] / red[128];
    __syncthreads();
    float s = rho_b[t];
    for (int k = 0; k < 128; ++k) s = fmaf(hp[k], rho_W[k * 128 + t], s);
    hr[t] = fmaxf(s, 0.f);
    __syncthreads();
    if (t < 4) {
        float l = cls_b[t];
        for (int k = 0; k < 128; ++k) l = fmaf(hr[k], cls_W[k * 4 + t], l);
        lg[t] = l;
    }
    __syncthreads();
    if (t == 0) {
        float hz[4], S[4];
        for (int c = 0; c < 4; ++c) hz[c] = 1.f / (1.f + expf(-lg[c]));
        S[0] = 1.f - hz[0];
        for (int c = 1; c < 4; ++c) S[c] = S[c - 1] * (1.f - hz[c]);
        int am = 0; float bm = lg[0];
        for (int c = 1; c < 4; ++c) if (lg[c] > bm) { bm = lg[c]; am = c; }
        out[0] = hz[0]; out[1] = hz[1]; out[2] = hz[2]; out[3] = hz[3];
        out[4] = S[0];  out[5] = S[1];  out[6] = S[2];  out[7] = S[3];
        out[8] = (float)am;
        out[9] = lg[0]; out[10] = lg[1]; out[11] = lg[2]; out[12] = lg[3];
    }
}

// ---------------------------------------------------------------------------
static inline int cdiv(int a, int b) { return (a + b - 1) / b; }

extern "C" void kernel_launch(void* const* d_in, const int* in_sizes, int n_in,
                              void* d_out, int out_size, void* d_ws, size_t ws_size,
                              hipStream_t stream) {
    const float* x      = (const float*)d_in[0];
    const int*   ei     = (const int*)d_in[1];
    const float* emb_W  = (const float*)d_in[2];
    const float* emb_b  = (const float*)d_in[3];
    const float* ln1_g  = (const float*)d_in[4];
    const float* ln1_b  = (const float*)d_in[5];
    const float* gat_Wl = (const float*)d_in[6];
    const float* gat_bl = (const float*)d_in[7];
    const float* gat_Wr = (const float*)d_in[8];
    const float* gat_br = (const float*)d_in[9];
    const float* gat_att  = (const float*)d_in[10];
    const float* gat_bias = (const float*)d_in[11];
    const float* mlp_w1[NBLK] = {(const float*)d_in[12], (const float*)d_in[14], (const float*)d_in[16]};
    const float* mlp_w2[NBLK] = {(const float*)d_in[13], (const float*)d_in[15], (const float*)d_in[17]};
    const float* attn_Wa = (const float*)d_in[18];
    const float* attn_ba = (const float*)d_in[19];
    const float* attn_Wb = (const float*)d_in[20];
    const float* attn_bb = (const float*)d_in[21];
    const float* attn_Wc = (const float*)d_in[22];
    const float* attn_bc = (const float*)d_in[23];
    const float* rho_W   = (const float*)d_in[24];
    const float* rho_b   = (const float*)d_in[25];
    const float* cls_W   = (const float*)d_in[26];
    const float* cls_b   = (const float*)d_in[27];
    float* out = (float*)d_out;

    const int N = in_sizes[0] / 512;   // 50000
    const int E = in_sizes[1] / 2;     // 800000
    const int* src = ei;
    const int* dst = ei + E;

    // ---- workspace layout ----
    char* base = (char*)d_ws;
    unsigned short* xb = (unsigned short*)base;                 // N*512 bf16 (51.2MB)
    float* bufA = (float*)base;                                 // alias xb (N*128 f32)
    float* bufB = bufA + (size_t)N * D;                         // alias xb
    float* H    = (float*)(base + (size_t)N * 512 * 2);         // N*128 f32
    unsigned short* Hb = (unsigned short*)(H + (size_t)N * D);  // N*128 bf16
    unsigned short* HN = Hb + (size_t)N * D;                    // N*128 bf16
    unsigned short* XL = HN + (size_t)N * D;                    // N*128 bf16
    unsigned short* XR = XL + (size_t)N * D;                    // N*128 bf16
    unsigned short* T  = HN;                                    // alias [HN|XL|XR]: N*384 bf16
    float* Avec = (float*)(XR + (size_t)N * D);                 // N
    float* red  = Avec + N;                                     // 132
    unsigned short* wbuf = (unsigned short*)(red + 132);        // 393216 bf16
    int* esrc   = (int*)(wbuf + 393216);                        // E
    int* deg    = esrc + E;                                     // N
    int* rowptr = deg + N;                                      // N+1
    int* fill   = rowptr + N + 1;                               // N
    int* bsum   = fill + N;                                     // 256

    // weight sub-buffers (bf16, transposed to [M][K])
    unsigned short* embT  = wbuf;                   // 128x512
    unsigned short* gatlT = wbuf + 65536;           // 3x 128x128
    unsigned short* gatrT = gatlT + 3 * 16384;
    unsigned short* w1T0  = gatrT + 3 * 16384;      // 128x128
    unsigned short* w1T1  = w1T0 + 16384;           // 256x128
    unsigned short* w1T2  = w1T1 + 32768;           // 384x128
    unsigned short* w2T0  = w1T2 + 49152;           // 128x128
    unsigned short* w2T1  = w2T0 + 16384;           // 128x256
    unsigned short* w2T2  = w2T1 + 32768;           // 128x384
    unsigned short* attaT = w2T2 + 49152;           // 128x128
    unsigned short* attbT = attaT + 16384;          // 128x128
    unsigned short* w1T[NBLK] = {w1T0, w1T1, w1T2};
    unsigned short* w2T[NBLK] = {w2T0, w2T1, w2T2};

    // ---- CSR build ----
    const int nb = cdiv(N, 256);
    zero_k<<<cdiv(N, 256), 256, 0, stream>>>(deg, fill, red, N);
    hist_k<<<cdiv(E, 256), 256, 0, stream>>>(dst, deg, E);
    blockscan_k<<<nb, 256, 0, stream>>>(deg, rowptr, bsum, N);
    scansums_k<<<1, 256, 0, stream>>>(bsum, nb);
    addoff_k<<<nb, 256, 0, stream>>>(rowptr, bsum, N);
    scatter_k<<<cdiv(E, 256), 256, 0, stream>>>(src, dst, rowptr, fill, esrc, E);

    // ---- input cast + weight prep ----
    xcast_k<<<cdiv(N * 512 / 4, 256), 256, 0, stream>>>(x, xb, (long)N * 512 / 4);
    {
        WPack p;
        p.w[0] = {emb_W, embT, 512, 128};
        for (int i = 0; i < 3; ++i) {
            p.w[1 + i] = {gat_Wl + (size_t)i * 16384, gatlT + (size_t)i * 16384, 128, 128};
            p.w[4 + i] = {gat_Wr + (size_t)i * 16384, gatrT + (size_t)i * 16384, 128, 128};
            const int h = D * (i + 1);
            p.w[7 + i]  = {mlp_w1[i], w1T[i], 128, h};
            p.w[10 + i] = {mlp_w2[i], w2T[i], h, 128};
        }
        p.w[13] = {attn_Wa, attaT, 128, 128};
        p.w[14] = {attn_Wb, attbT, 128, 128};
        wprep_k<<<dim3(64, 15), 256, 0, stream>>>(p);
    }

    const int gx = cdiv(N, GBM);

    // ---- embedding: H = relu(x @ emb_W + emb_b) ----
    mgemm_k<1, true, false, true, false><<<dim3(gx, 2), 256, 0, stream>>>(
        xb, embT, emb_b, H, nullptr, N, 512, 128);

    // ---- 3 blocks ----
    for (int i = 0; i < NBLK; ++i) {
        ln_k<<<cdiv(N, 4), 256, 0, stream>>>(H, ln1_g + i * D, ln1_b + i * D, HN, N);
        mgemm_k<0, true, false, false, true><<<dim3(gx, 2), 256, 0, stream>>>(
            HN, gatlT + (size_t)i * 16384, gat_bl + i * D, nullptr, XL, N, 128, 128);
        mgemm_k<0, true, false, false, true><<<dim3(gx, 2), 256, 0, stream>>>(
            HN, gatrT + (size_t)i * 16384, gat_br + i * D, nullptr, XR, N, 128, 128);
        gat_k<<<cdiv(N, 4), 256, 0, stream>>>(XL, XR, gat_att + i * D, gat_bias + i * D,
                                              rowptr, esrc, H, Hb, N);
        const int h = D * (i + 1);
        mgemm_k<2, false, false, false, true><<<dim3(gx, h / 64), 256, 0, stream>>>(
            Hb, w1T[i], nullptr, nullptr, T, N, 128, h);
        mgemm_k<0, false, true, true, true><<<dim3(gx, 2), 256, 0, stream>>>(
            T, w2T[i], nullptr, H, Hb, N, h, 128);
    }

    // ---- gated attention pooling ----
    mgemm_k<3, true, false, true, false><<<dim3(gx, 2), 256, 0, stream>>>(
        Hb, attaT, attn_ba, bufA, nullptr, N, 128, 128);
    mgemm_k<4, true, false, true, false><<<dim3(gx, 2), 256, 0, stream>>>(
        Hb, attbT, attn_bb, bufB, nullptr, N, 128, 128);
    poolA_k<<<cdiv(N, 4), 256, 0, stream>>>(bufA, bufB, attn_Wc, attn_bc, Avec, N);
    maxA_k<<<1, 1024, 0, stream>>>(Avec, red, N);
    wsum_k<<<120, 256, 0, stream>>>(Avec, H, red, N);
    final_k<<<1, 128, 0, stream>>>(red, rho_W, rho_b, cls_W, cls_b, out);
}

// Round 3
// 841.966 us; speedup vs baseline: 2.1231x; 1.2377x over previous
//
#include <hip/hip_runtime.h>
#include <math.h>

// ---------------------------------------------------------------------------
// GraphMixer forward, round 3:
//   - gat3_k: quarter-wave (16-lane) per edge, 4 edges in flight per wave,
//     max-free softmax (scores bounded), 16B bf16 gathers
//   - mgemm_k: BM=64,BN=128,BK=32 bf16 MFMA; stacked Wl|Wr and Wa|Wb GEMMs
// ---------------------------------------------------------------------------

#define D 128
#define NBLK 3

typedef __attribute__((ext_vector_type(8))) short bf16x8;
typedef __attribute__((ext_vector_type(4))) float f32x4;

static __device__ __forceinline__ float wred_sum(float v) {
#pragma unroll
    for (int m = 1; m < 64; m <<= 1) v += __shfl_xor(v, m, 64);
    return v;
}

static __device__ __forceinline__ float bf2f(unsigned short u) {
    union { unsigned i; float f; } c; c.i = ((unsigned)u) << 16; return c.f;
}
static __device__ __forceinline__ unsigned short f2bf(float f) {
    union { float f; unsigned i; } c; c.f = f;
    unsigned r = c.i + 0x7fff + ((c.i >> 16) & 1);
    return (unsigned short)(r >> 16);
}

static __device__ __forceinline__ void gl16(const unsigned short* g, unsigned short* l) {
    __builtin_amdgcn_global_load_lds((const __attribute__((address_space(1))) void*)g,
                                     (__attribute__((address_space(3))) void*)l, 16, 0, 0);
}

// ---------------- CSR build ----------------
__global__ void zero_k(int* deg, int* fill, float* red, int n) {
    int i = blockIdx.x * blockDim.x + threadIdx.x;
    if (i < n) { deg[i] = 0; fill[i] = 0; }
    if (i < 132) red[i] = 0.f;
}

__global__ void hist_k(const int* __restrict__ dst, int* __restrict__ deg, int E) {
    int e = blockIdx.x * blockDim.x + threadIdx.x;
    if (e < E) atomicAdd(&deg[dst[e]], 1);
}

__global__ __launch_bounds__(256) void blockscan_k(const int* __restrict__ deg,
                                                   int* __restrict__ rowptr,
                                                   int* __restrict__ bsum, int n) {
    __shared__ int tmp[256];
    const int tid = threadIdx.x;
    const int i = blockIdx.x * 256 + tid;
    int v = (i < n) ? deg[i] : 0;
    tmp[tid] = v;
    __syncthreads();
#pragma unroll
    for (int off = 1; off < 256; off <<= 1) {
        int t = (tid >= off) ? tmp[tid - off] : 0;
        __syncthreads();
        tmp[tid] += t;
        __syncthreads();
    }
    if (i < n) rowptr[i + 1] = tmp[tid];
    if (tid == 255) bsum[blockIdx.x] = tmp[255];
}

__global__ __launch_bounds__(256) void scansums_k(int* __restrict__ bsum, int nb) {
    __shared__ int tmp[256];
    const int tid = threadIdx.x;
    int v = (tid < nb) ? bsum[tid] : 0;
    tmp[tid] = v;
    __syncthreads();
#pragma unroll
    for (int off = 1; off < 256; off <<= 1) {
        int t = (tid >= off) ? tmp[tid - off] : 0;
        __syncthreads();
        tmp[tid] += t;
        __syncthreads();
    }
    if (tid < nb) bsum[tid] = tmp[tid];
}

__global__ __launch_bounds__(256) void addoff_k(int* __restrict__ rowptr,
                                                const int* __restrict__ bsum, int n) {
    int i = blockIdx.x * 256 + threadIdx.x;
    if (i == 0) rowptr[0] = 0;
    if (i < n && blockIdx.x > 0) rowptr[i + 1] += bsum[blockIdx.x - 1];
}

__global__ void scatter_k(const int* __restrict__ src, const int* __restrict__ dst,
                          const int* __restrict__ rowptr, int* __restrict__ fill,
                          int* __restrict__ esrc, int E) {
    int e = blockIdx.x * blockDim.x + threadIdx.x;
    if (e < E) {
        int d = dst[e];
        int pos = rowptr[d] + atomicAdd(&fill[d], 1);
        esrc[pos] = src[e];
    }
}

// ---------------- casts / weight & bias prep ----------------
__global__ void xcast_k(const float* __restrict__ x, unsigned short* __restrict__ xb,
                        long n4) {
    long i = (long)blockIdx.x * blockDim.x + threadIdx.x;
    if (i >= n4) return;
    float4 v = ((const float4*)x)[i];
    ushort4 o;
    o.x = f2bf(v.x); o.y = f2bf(v.y); o.z = f2bf(v.z); o.w = f2bf(v.w);
    ((ushort4*)xb)[i] = o;
}

struct WDesc { const float* s; unsigned short* d; int K; int M; };
struct WPack { WDesc w[15]; };

__global__ void wprep_k(WPack p) {
    WDesc d = p.w[blockIdx.y];
    const int total = d.K * d.M;
    for (int i = blockIdx.x * 256 + threadIdx.x; i < total; i += gridDim.x * 256) {
        int m = i % d.M, k = i / d.M;            // src row-major [K][M]
        d.d[(size_t)m * d.K + k] = f2bf(d.s[i]); // dst [M][K]
    }
}

// stacked biases: sb[i][256] = [bl_i | br_i] (i<3), sb[3][256] = [ba | bb]
__global__ __launch_bounds__(256) void bcat_k(const float* bl, const float* br,
                                              const float* ba, const float* bb,
                                              float* sb) {
    const int t = threadIdx.x;
    for (int i = 0; i < 3; ++i)
        sb[i * 256 + t] = (t < 128) ? bl[i * 128 + t] : br[i * 128 + t - 128];
    sb[3 * 256 + t] = (t < 128) ? ba[t] : bb[t - 128];
}

// ---------------- bf16 MFMA GEMM: C = act(A @ BT^T [+bias]) [+C32] ----------
// A: [N][K] bf16, BT: [M][K] bf16, K%32==0, M%128==0. BM=64, BN=128.
#define GBK 32

template <int ACT, bool BIAS, bool ACC, bool W32, bool W16>
__global__ __launch_bounds__(256) void mgemm_k(const unsigned short* __restrict__ A,
                                               const unsigned short* __restrict__ BT,
                                               const float* __restrict__ bias,
                                               float* __restrict__ C32,
                                               unsigned short* __restrict__ C16,
                                               int N, int K, int M) {
    // LDS chunk layout: group g (16 rows) at [g*512]; within group chunk l = c8*16+r16
    __shared__ unsigned short Als[64 * GBK];   // 4 KB
    __shared__ unsigned short Bls[128 * GBK];  // 8 KB
    const int t = threadIdx.x;
    const int w = t >> 6;          // wave 0..3
    const int l = t & 63;
    const int c8 = l >> 4, r16 = l & 15;
    const int row0 = blockIdx.x * 64;
    const int col0 = blockIdx.y * 128;

    int arow = row0 + w * 16 + r16; if (arow > N - 1) arow = N - 1;
    const unsigned short* gA  = A + (size_t)arow * K + c8 * 8;
    const unsigned short* gB0 = BT + (size_t)(col0 + w * 16 + r16) * K + c8 * 8;
    const unsigned short* gB1 = BT + (size_t)(col0 + (w + 4) * 16 + r16) * K + c8 * 8;

    f32x4 acc[4][2];
#pragma unroll
    for (int i = 0; i < 4; ++i)
#pragma unroll
        for (int j = 0; j < 2; ++j) acc[i][j] = (f32x4){0.f, 0.f, 0.f, 0.f};

    for (int k0 = 0; k0 < K; k0 += GBK) {
        gl16(gA + k0,  &Als[w * 512]);
        gl16(gB0 + k0, &Bls[w * 512]);
        gl16(gB1 + k0, &Bls[(w + 4) * 512]);
        __syncthreads();
        bf16x8 b0 = *(const bf16x8*)&Bls[((w * 2 + 0) * 64 + l) * 8];
        bf16x8 b1 = *(const bf16x8*)&Bls[((w * 2 + 1) * 64 + l) * 8];
#pragma unroll
        for (int tm = 0; tm < 4; ++tm) {
            bf16x8 a = *(const bf16x8*)&Als[(tm * 64 + l) * 8];
            acc[tm][0] = __builtin_amdgcn_mfma_f32_16x16x32_bf16(a, b0, acc[tm][0], 0, 0, 0);
            acc[tm][1] = __builtin_amdgcn_mfma_f32_16x16x32_bf16(a, b1, acc[tm][1], 0, 0, 0);
        }
        __syncthreads();
    }

    // epilogue: C/D layout col=lane&15, row=c8*4+reg
#pragma unroll
    for (int tn = 0; tn < 2; ++tn) {
        const int col = col0 + (w * 2 + tn) * 16 + r16;
        float bv = 0.f;
        if (BIAS) bv = bias[col];
#pragma unroll
        for (int tm = 0; tm < 4; ++tm) {
#pragma unroll
            for (int r = 0; r < 4; ++r) {
                const int row = row0 + tm * 16 + c8 * 4 + r;
                if (row >= N) continue;
                float xv = acc[tm][tn][r] + bv;
                if (ACT == 1) xv = fmaxf(xv, 0.f);
                else if (ACT == 2) xv = 0.5f * xv * (1.f + erff(xv * 0.70710678118654752f));
                else if (ACT == 5) xv = (col < 128) ? tanhf(xv) : 1.f / (1.f + expf(-xv));
                if (ACC) xv += C32[(size_t)row * M + col];
                if (W32) C32[(size_t)row * M + col] = xv;
                if (W16) C16[(size_t)row * M + col] = f2bf(xv);
            }
        }
    }
}

// ---------------- LayerNorm: H fp32 -> HN bf16 (wave per node) --------------
__global__ __launch_bounds__(256) void ln_k(const float* __restrict__ H,
                                            const float* __restrict__ g,
                                            const float* __restrict__ b,
                                            unsigned short* __restrict__ HN, int n) {
    const int l = threadIdx.x & 63;
    const int node = blockIdx.x * 4 + (threadIdx.x >> 6);
    if (node >= n) return;
    const float2 v = *(const float2*)&H[(size_t)node * D + 2 * l];
    const float mu = wred_sum(v.x + v.y) * (1.f / 128.f);
    const float dx = v.x - mu, dy = v.y - mu;
    const float var = wred_sum(dx * dx + dy * dy) * (1.f / 128.f);
    const float rs = rsqrtf(var + 1e-5f);
    ushort2 st;
    st.x = f2bf(dx * rs * g[2 * l] + b[2 * l]);
    st.y = f2bf(dy * rs * g[2 * l + 1] + b[2 * l + 1]);
    *(ushort2*)&HN[(size_t)node * D + 2 * l] = st;
}

// ------- GATv2: quarter-wave per edge, max-free softmax ---------------------
// X: [N][256] bf16 = [xl | xr]
__global__ __launch_bounds__(256) void gat3_k(const unsigned short* __restrict__ X,
                                              const float* __restrict__ att,
                                              const float* __restrict__ gbias,
                                              const int* __restrict__ rowptr,
                                              const int* __restrict__ esrc,
                                              float* __restrict__ H,
                                              unsigned short* __restrict__ Hb, int n) {
    const int l = threadIdx.x & 63;
    const int node = blockIdx.x * 4 + (threadIdx.x >> 6);
    if (node >= n) return;
    const int q = l >> 4;
    const int d0 = (l & 15) * 8;

    float a8[8], xr[8], xs[8];
    {
        const float4 t0 = *(const float4*)&att[d0];
        const float4 t1 = *(const float4*)&att[d0 + 4];
        a8[0] = t0.x; a8[1] = t0.y; a8[2] = t0.z; a8[3] = t0.w;
        a8[4] = t1.x; a8[5] = t1.y; a8[6] = t1.z; a8[7] = t1.w;
        const bf16x8 uxs = *(const bf16x8*)&X[(size_t)node * 256 + d0];
        const bf16x8 uxr = *(const bf16x8*)&X[(size_t)node * 256 + 128 + d0];
#pragma unroll
        for (int j = 0; j < 8; ++j) {
            xs[j] = bf2f((unsigned short)uxs[j]);
            xr[j] = bf2f((unsigned short)uxr[j]);
        }
    }

    // self-loop score (identical in all quarters; only q==0 accumulates)
    float sc = 0.f;
#pragma unroll
    for (int j = 0; j < 8; ++j) {
        const float e = xs[j] + xr[j];
        sc = fmaf(a8[j], fmaxf(e, 0.2f * e), sc);
    }
#pragma unroll
    for (int m = 1; m < 16; m <<= 1) sc += __shfl_xor(sc, m, 64);
    const float wself = __expf(sc);
    float dsum = (q == 0) ? wself : 0.f;
    float acc[8];
#pragma unroll
    for (int j = 0; j < 8; ++j) acc[j] = (q == 0) ? wself * xs[j] : 0.f;

    const int p0 = rowptr[node], p1 = rowptr[node + 1];
    for (int p = p0 + q; p < p1; p += 4) {
        const int s = esrc[p];
        const bf16x8 ux = *(const bf16x8*)&X[(size_t)s * 256 + d0];
        float xl[8];
#pragma unroll
        for (int j = 0; j < 8; ++j) xl[j] = bf2f((unsigned short)ux[j]);
        float e_sc = 0.f;
#pragma unroll
        for (int j = 0; j < 8; ++j) {
            const float e = xl[j] + xr[j];
            e_sc = fmaf(a8[j], fmaxf(e, 0.2f * e), e_sc);
        }
#pragma unroll
        for (int m = 1; m < 16; m <<= 1) e_sc += __shfl_xor(e_sc, m, 64);
        const float wgt = __expf(e_sc);
        dsum += wgt;
#pragma unroll
        for (int j = 0; j < 8; ++j) acc[j] = fmaf(wgt, xl[j], acc[j]);
    }

    // merge the 4 quarters
#pragma unroll
    for (int m = 16; m < 64; m <<= 1) {
        dsum += __shfl_xor(dsum, m, 64);
#pragma unroll
        for (int j = 0; j < 8; ++j) acc[j] += __shfl_xor(acc[j], m, 64);
    }

    if (q == 0) {
        const float inv = 1.f / dsum;
        const size_t o = (size_t)node * D + d0;
        float4 h0 = *(const float4*)&H[o];
        float4 h1 = *(const float4*)&H[o + 4];
        float hv[8] = {h0.x, h0.y, h0.z, h0.w, h1.x, h1.y, h1.z, h1.w};
        bf16x8 hb;
#pragma unroll
        for (int j = 0; j < 8; ++j) {
            hv[j] += acc[j] * inv + gbias[d0 + j];
            hb[j] = (short)f2bf(hv[j]);
        }
        *(float4*)&H[o]     = make_float4(hv[0], hv[1], hv[2], hv[3]);
        *(float4*)&H[o + 4] = make_float4(hv[4], hv[5], hv[6], hv[7]);
        *(bf16x8*)&Hb[o] = hb;
    }
}

// ---------------- pooling ----------------
// P: [N][256] f32 = [tanh(a) | sigmoid(b)]
__global__ __launch_bounds__(256) void poolA_k(const float* __restrict__ P,
                                               const float* __restrict__ Wc,
                                               const float* __restrict__ bc,
                                               float* __restrict__ A, int n) {
    const int lane = threadIdx.x & 63;
    const int node = blockIdx.x * 4 + (threadIdx.x >> 6);
    if (node >= n) return;
    const size_t o = (size_t)node * 256;
    const float v = wred_sum(P[o + lane] * P[o + 128 + lane] * Wc[lane] +
                             P[o + 64 + lane] * P[o + 192 + lane] * Wc[64 + lane]);
    if (lane == 0) A[node] = v + bc[0];
}

__global__ __launch_bounds__(1024) void maxA_k(const float* __restrict__ A,
                                               float* __restrict__ red, int n) {
    __shared__ float sm[1024];
    float m = -3.4e38f;
    for (int i = threadIdx.x; i < n; i += 1024) m = fmaxf(m, A[i]);
    sm[threadIdx.x] = m;
    __syncthreads();
    for (int s = 512; s > 0; s >>= 1) {
        if (threadIdx.x < s) sm[threadIdx.x] = fmaxf(sm[threadIdx.x], sm[threadIdx.x + s]);
        __syncthreads();
    }
    if (threadIdx.x == 0) red[129] = sm[0];
}

__global__ __launch_bounds__(256) void wsum_k(const float* __restrict__ A,
                                              const float* __restrict__ H,
                                              float* __restrict__ red, int n) {
    const int lane = threadIdx.x & 63;
    const int gw = blockIdx.x * 4 + (threadIdx.x >> 6);
    const int nw = gridDim.x * 4;
    const float maxA = red[129];
    float a0 = 0.f, a1 = 0.f, dn = 0.f;
    for (int node = gw; node < n; node += nw) {
        const float w = expf(A[node] - maxA);
        dn += w;
        a0 = fmaf(w, H[(size_t)node * D + lane], a0);
        a1 = fmaf(w, H[(size_t)node * D + 64 + lane], a1);
    }
    atomicAdd(&red[lane], a0);
    atomicAdd(&red[64 + lane], a1);
    if (lane == 0) atomicAdd(&red[128], dn);
}

__global__ __launch_bounds__(128) void final_k(const float* __restrict__ red,
                                               const float* __restrict__ rho_W,
                                               const float* __restrict__ rho_b,
                                               const float* __restrict__ cls_W,
                                               const float* __restrict__ cls_b,
                                               float* __restrict__ out) {
    __shared__ float hp[128];
    __shared__ float hr[128];
    __shared__ float lg[4];
    const int t = threadIdx.x;
    hp[t] = red[t] / red[128];
    __syncthreads();
    float s = rho_b[t];
    for (int k = 0; k < 128; ++k) s = fmaf(hp[k], rho_W[k * 128 + t], s);
    hr[t] = fmaxf(s, 0.f);
    __syncthreads();
    if (t < 4) {
        float l = cls_b[t];
        for (int k = 0; k < 128; ++k) l = fmaf(hr[k], cls_W[k * 4 + t], l);
        lg[t] = l;
    }
    __syncthreads();
    if (t == 0) {
        float hz[4], S[4];
        for (int c = 0; c < 4; ++c) hz[c] = 1.f / (1.f + expf(-lg[c]));
        S[0] = 1.f - hz[0];
        for (int c = 1; c < 4; ++c) S[c] = S[c - 1] * (1.f - hz[c]);
        int am = 0; float bm = lg[0];
        for (int c = 1; c < 4; ++c) if (lg[c] > bm) { bm = lg[c]; am = c; }
        out[0] = hz[0]; out[1] = hz[1]; out[2] = hz[2]; out[3] = hz[3];
        out[4] = S[0];  out[5] = S[1];  out[6] = S[2];  out[7] = S[3];
        out[8] = (float)am;
        out[9] = lg[0]; out[10] = lg[1]; out[11] = lg[2]; out[12] = lg[3];
    }
}

// ---------------------------------------------------------------------------
static inline int cdiv(int a, int b) { return (a + b - 1) / b; }

extern "C" void kernel_launch(void* const* d_in, const int* in_sizes, int n_in,
                              void* d_out, int out_size, void* d_ws, size_t ws_size,
                              hipStream_t stream) {
    const float* x      = (const float*)d_in[0];
    const int*   ei     = (const int*)d_in[1];
    const float* emb_W  = (const float*)d_in[2];
    const float* emb_b  = (const float*)d_in[3];
    const float* ln1_g  = (const float*)d_in[4];
    const float* ln1_b  = (const float*)d_in[5];
    const float* gat_Wl = (const float*)d_in[6];
    const float* gat_bl = (const float*)d_in[7];
    const float* gat_Wr = (const float*)d_in[8];
    const float* gat_br = (const float*)d_in[9];
    const float* gat_att  = (const float*)d_in[10];
    const float* gat_bias = (const float*)d_in[11];
    const float* mlp_w1[NBLK] = {(const float*)d_in[12], (const float*)d_in[14], (const float*)d_in[16]};
    const float* mlp_w2[NBLK] = {(const float*)d_in[13], (const float*)d_in[15], (const float*)d_in[17]};
    const float* attn_Wa = (const float*)d_in[18];
    const float* attn_ba = (const float*)d_in[19];
    const float* attn_Wb = (const float*)d_in[20];
    const float* attn_bb = (const float*)d_in[21];
    const float* attn_Wc = (const float*)d_in[22];
    const float* attn_bc = (const float*)d_in[23];
    const float* rho_W   = (const float*)d_in[24];
    const float* rho_b   = (const float*)d_in[25];
    const float* cls_W   = (const float*)d_in[26];
    const float* cls_b   = (const float*)d_in[27];
    float* out = (float*)d_out;

    const int N = in_sizes[0] / 512;   // 50000
    const int E = in_sizes[1] / 2;     // 800000
    const int* src = ei;
    const int* dst = ei + E;

    // ---- workspace layout ----
    char* base = (char*)d_ws;
    unsigned short* xb = (unsigned short*)base;                 // N*512 bf16 (51.2MB)
    float* P = (float*)base;                                    // alias: N*256 f32
    float* H = (float*)(base + (size_t)N * 512 * 2);            // N*128 f32
    unsigned short* Hb = (unsigned short*)(H + (size_t)N * D);  // N*128 bf16
    unsigned short* HN = Hb + (size_t)N * D;                    // N*128 bf16
    unsigned short* X  = HN + (size_t)N * D;                    // N*256 bf16 [xl|xr]
    unsigned short* T  = HN;                                    // alias HN+X: N*384 bf16
    float* Avec = (float*)(X + (size_t)N * 256);                // N
    float* red  = Avec + N;                                     // 132
    float* sb   = red + 132;                                    // 4*256 stacked biases
    unsigned short* wbuf = (unsigned short*)(sb + 1024);        // 393216 bf16
    int* esrc   = (int*)(wbuf + 393216);                        // E
    int* deg    = esrc + E;                                     // N
    int* rowptr = deg + N;                                      // N+1
    int* fill   = rowptr + N + 1;                               // N
    int* bsum   = fill + N;                                     // 256

    // weight sub-buffers (bf16, transposed to [M][K])
    unsigned short* embT = wbuf;                    // 128x512
    unsigned short* gatT = wbuf + 65536;            // 3x 256x128 (Wl|Wr stacked)
    unsigned short* w1T0 = gatT + 3 * 32768;        // 128x128
    unsigned short* w1T1 = w1T0 + 16384;            // 256x128
    unsigned short* w1T2 = w1T1 + 32768;            // 384x128
    unsigned short* w2T0 = w1T2 + 49152;            // 128x128
    unsigned short* w2T1 = w2T0 + 16384;            // 128x256
    unsigned short* w2T2 = w2T1 + 32768;            // 128x384
    unsigned short* attT = w2T2 + 49152;            // 256x128 (Wa|Wb stacked)
    unsigned short* w1T[NBLK] = {w1T0, w1T1, w1T2};
    unsigned short* w2T[NBLK] = {w2T0, w2T1, w2T2};

    // ---- CSR build ----
    const int nb = cdiv(N, 256);
    zero_k<<<cdiv(N, 256), 256, 0, stream>>>(deg, fill, red, N);
    hist_k<<<cdiv(E, 256), 256, 0, stream>>>(dst, deg, E);
    blockscan_k<<<nb, 256, 0, stream>>>(deg, rowptr, bsum, N);
    scansums_k<<<1, 256, 0, stream>>>(bsum, nb);
    addoff_k<<<nb, 256, 0, stream>>>(rowptr, bsum, N);
    scatter_k<<<cdiv(E, 256), 256, 0, stream>>>(src, dst, rowptr, fill, esrc, E);

    // ---- input cast + weight/bias prep ----
    xcast_k<<<cdiv(N * 512 / 4, 256), 256, 0, stream>>>(x, xb, (long)N * 512 / 4);
    {
        WPack p;
        p.w[0] = {emb_W, embT, 512, 128};
        for (int i = 0; i < 3; ++i) {
            p.w[1 + i] = {gat_Wl + (size_t)i * 16384, gatT + (size_t)i * 32768, 128, 128};
            p.w[4 + i] = {gat_Wr + (size_t)i * 16384, gatT + (size_t)i * 32768 + 16384, 128, 128};
            const int h = D * (i + 1);
            p.w[7 + i]  = {mlp_w1[i], w1T[i], 128, h};
            p.w[10 + i] = {mlp_w2[i], w2T[i], h, 128};
        }
        p.w[13] = {attn_Wa, attT, 128, 128};
        p.w[14] = {attn_Wb, attT + 16384, 128, 128};
        wprep_k<<<dim3(64, 15), 256, 0, stream>>>(p);
    }
    bcat_k<<<1, 256, 0, stream>>>(gat_bl, gat_br, attn_ba, attn_bb, sb);

    const int gx = cdiv(N, 64);   // 782

    // ---- embedding: H = relu(x @ emb_W + emb_b) ----
    mgemm_k<1, true, false, true, false><<<dim3(gx, 1), 256, 0, stream>>>(
        xb, embT, emb_b, H, nullptr, N, 512, 128);

    // ---- 3 blocks ----
    for (int i = 0; i < NBLK; ++i) {
        ln_k<<<cdiv(N, 4), 256, 0, stream>>>(H, ln1_g + i * D, ln1_b + i * D, HN, N);
        // X = HN @ [Wl|Wr] + [bl|br]  (M=256)
        mgemm_k<0, true, false, false, true><<<dim3(gx, 2), 256, 0, stream>>>(
            HN, gatT + (size_t)i * 32768, sb + i * 256, nullptr, X, N, 128, 256);
        gat3_k<<<cdiv(N, 4), 256, 0, stream>>>(X, gat_att + i * D, gat_bias + i * D,
                                               rowptr, esrc, H, Hb, N);
        const int h = D * (i + 1);
        mgemm_k<2, false, false, false, true><<<dim3(gx, h / 128), 256, 0, stream>>>(
            Hb, w1T[i], nullptr, nullptr, T, N, 128, h);
        mgemm_k<0, false, true, true, true><<<dim3(gx, 1), 256, 0, stream>>>(
            T, w2T[i], nullptr, H, Hb, N, h, 128);
    }

    // ---- gated attention pooling ----
    mgemm_k<5, true, false, true, false><<<dim3(gx, 2), 256, 0, stream>>>(
        Hb, attT, sb + 3 * 256, P, nullptr, N, 128, 256);
    poolA_k<<<cdiv(N, 4), 256, 0, stream>>>(P, attn_Wc, attn_bc, Avec, N);
    maxA_k<<<1, 1024, 0, stream>>>(Avec, red, N);
    wsum_k<<<120, 256, 0, stream>>>(Avec, H, red, N);
    final_k<<<1, 128, 0, stream>>>(red, rho_W, rho_b, cls_W, cls_b, out);
}

// Round 4
// 771.968 us; speedup vs baseline: 2.3157x; 1.0907x over previous
//
#include <hip/hip_runtime.h>
#include <math.h>

// ---------------------------------------------------------------------------
// GraphMixer forward, round 4:
//   - rgemm_k: B-resident-in-LDS GEMM (weights pre-chunked into MFMA fragment
//     order, staged once via global_load_lds, ONE barrier, register-resident A)
//   - LN fused into GAT projection GEMM (quad-shuffle row stats)
//   - no bf16 shadow of H (A loaded fp32, converted in-reg); no xcast
//   - max-free softmax in both GAT (R3-proven) and pooling
// ---------------------------------------------------------------------------

#define D 128
#define NBLK 3

typedef __attribute__((ext_vector_type(8))) short bf16x8;
typedef __attribute__((ext_vector_type(4))) float f32x4;

static __device__ __forceinline__ float wred_sum(float v) {
#pragma unroll
    for (int m = 1; m < 64; m <<= 1) v += __shfl_xor(v, m, 64);
    return v;
}

static __device__ __forceinline__ float bf2f(unsigned short u) {
    union { unsigned i; float f; } c; c.i = ((unsigned)u) << 16; return c.f;
}
static __device__ __forceinline__ unsigned short f2bf(float f) {
    union { float f; unsigned i; } c; c.f = f;
    unsigned r = c.i + 0x7fff + ((c.i >> 16) & 1);
    return (unsigned short)(r >> 16);
}

static __device__ __forceinline__ void gl16(const unsigned short* g, unsigned short* l) {
    __builtin_amdgcn_global_load_lds((const __attribute__((address_space(1))) void*)g,
                                     (__attribute__((address_space(3))) void*)l, 16, 0, 0);
}

// ---------------- CSR build ----------------
__global__ void zero_k(int* deg, int* fill, float* red, int n) {
    int i = blockIdx.x * blockDim.x + threadIdx.x;
    if (i < n) { deg[i] = 0; fill[i] = 0; }
    if (i < 132) red[i] = 0.f;
}

__global__ void hist_k(const int* __restrict__ dst, int* __restrict__ deg, int E) {
    int e = blockIdx.x * blockDim.x + threadIdx.x;
    if (e < E) atomicAdd(&deg[dst[e]], 1);
}

__global__ __launch_bounds__(256) void blockscan_k(const int* __restrict__ deg,
                                                   int* __restrict__ rowptr,
                                                   int* __restrict__ bsum, int n) {
    __shared__ int tmp[256];
    const int tid = threadIdx.x;
    const int i = blockIdx.x * 256 + tid;
    int v = (i < n) ? deg[i] : 0;
    tmp[tid] = v;
    __syncthreads();
#pragma unroll
    for (int off = 1; off < 256; off <<= 1) {
        int t = (tid >= off) ? tmp[tid - off] : 0;
        __syncthreads();
        tmp[tid] += t;
        __syncthreads();
    }
    if (i < n) rowptr[i + 1] = tmp[tid];
    if (tid == 255) bsum[blockIdx.x] = tmp[255];
}

__global__ __launch_bounds__(256) void scansums_k(int* __restrict__ bsum, int nb) {
    __shared__ int tmp[256];
    const int tid = threadIdx.x;
    int v = (tid < nb) ? bsum[tid] : 0;
    tmp[tid] = v;
    __syncthreads();
#pragma unroll
    for (int off = 1; off < 256; off <<= 1) {
        int t = (tid >= off) ? tmp[tid - off] : 0;
        __syncthreads();
        tmp[tid] += t;
        __syncthreads();
    }
    if (tid < nb) bsum[tid] = tmp[tid];
}

__global__ __launch_bounds__(256) void addoff_k(int* __restrict__ rowptr,
                                                const int* __restrict__ bsum, int n) {
    int i = blockIdx.x * 256 + threadIdx.x;
    if (i == 0) rowptr[0] = 0;
    if (i < n && blockIdx.x > 0) rowptr[i + 1] += bsum[blockIdx.x - 1];
}

__global__ void scatter_k(const int* __restrict__ src, const int* __restrict__ dst,
                          const int* __restrict__ rowptr, int* __restrict__ fill,
                          int* __restrict__ esrc, int E) {
    int e = blockIdx.x * blockDim.x + threadIdx.x;
    if (e < E) {
        int d = dst[e];
        int pos = rowptr[d] + atomicAdd(&fill[d], 1);
        esrc[pos] = src[e];
    }
}

// ---------------- weight prep: [K][M] f32 -> chunked bf16 fragment order ----
// chunk order: (t = m/16 outer, c = k/32, lane l) ; elem j :
//   dst[((t*(K/32)+c)*64+l)*8+j] = bf16(src[(c*32+(l>>4)*8+j)*M + t*16+(l&15)])
struct WDesc { const float* s; unsigned short* d; int K; int M; };
struct WPack { WDesc w[16]; };

__global__ __launch_bounds__(256) void wprep_k(WPack p) {
    WDesc d = p.w[blockIdx.y];
    const int nc = d.K / 32;
    const int chunks = (d.M / 16) * nc * 64;
    for (int i = blockIdx.x * 256 + threadIdx.x; i < chunks; i += gridDim.x * 256) {
        const int l = i & 63;
        const int c = (i >> 6) % nc;
        const int t = i / (64 * nc);
        const int m = t * 16 + (l & 15);
        const int kb = c * 32 + ((l >> 4) & 3) * 8;
#pragma unroll
        for (int j = 0; j < 8; ++j)
            d.d[(size_t)i * 8 + j] = f2bf(d.s[(size_t)(kb + j) * d.M + m]);
    }
}

// stacked biases: sb[i][256] = [bl_i | br_i] (i<3), sb[3][256] = [ba | bb]
__global__ __launch_bounds__(256) void bcat_k(const float* bl, const float* br,
                                              const float* ba, const float* bb,
                                              float* sb) {
    const int t = threadIdx.x;
    for (int i = 0; i < 3; ++i)
        sb[i * 256 + t] = (t < 128) ? bl[i * 128 + t] : br[i * 128 + t - 128];
    sb[3 * 256 + t] = (t < 128) ? ba[t] : bb[t - 128];
}

// ---------------- B-resident MFMA GEMM ----------------
// C[row][col] = act( A[row][koff:koff+TK] . B + bias ) (+C32 pre-act via ACC)
// B pre-chunked; slice y covers cols [y*TBN, (y+1)*TBN). BM=64 rows/block.
template <int TK, int TBN, int ACT, bool BIAS, bool ACC, bool LNM, bool A16,
          bool W32, bool W16>
__global__ __launch_bounds__(256) void rgemm_k(const void* __restrict__ Ap,
                                               const unsigned short* __restrict__ BTc,
                                               const float* __restrict__ bias,
                                               const float* __restrict__ lng,
                                               const float* __restrict__ lnb,
                                               float* __restrict__ C32,
                                               unsigned short* __restrict__ C16,
                                               int N, int strideA, int koff, int M) {
    constexpr int NC = TK / 32;
    constexpr int NT = TBN / 16;
    __shared__ unsigned short Bls[TBN * TK];   // <= 64 KB
    const int tid = threadIdx.x;
    const int w = tid >> 6, l = tid & 63;
    const int q = l >> 4;

    // ---- stage B slice (linear, one-shot) ----
    const unsigned short* bsrc = BTc + (size_t)blockIdx.y * (NT * NC * 512);
    constexpr int ITER = (TBN * TK / 8) / 256;
#pragma unroll
    for (int i = 0; i < ITER; ++i) {
        const int idx = i * 256 + tid;
        gl16(bsrc + (size_t)idx * 8, &Bls[idx * 8]);
    }

    // ---- register-resident A fragments (16 rows x TK per wave) ----
    int r = blockIdx.x * 64 + w * 16 + (l & 15);
    if (r > N - 1) r = N - 1;
    bf16x8 afr[NC];
    if (A16) {
        const unsigned short* A = (const unsigned short*)Ap;
#pragma unroll
        for (int c = 0; c < NC; ++c)
            afr[c] = *(const bf16x8*)(A + (size_t)r * strideA + koff + c * 32 + q * 8);
    } else {
        const float* A = (const float*)Ap;
        float av[NC][8];
#pragma unroll
        for (int c = 0; c < NC; ++c) {
            const float* ap = A + (size_t)r * strideA + koff + c * 32 + q * 8;
            const float4 v0 = *(const float4*)ap;
            const float4 v1 = *(const float4*)(ap + 4);
            av[c][0] = v0.x; av[c][1] = v0.y; av[c][2] = v0.z; av[c][3] = v0.w;
            av[c][4] = v1.x; av[c][5] = v1.y; av[c][6] = v1.z; av[c][7] = v1.w;
        }
        if (LNM) {   // layernorm over the row (lanes l, l^16, l^32, l^48 share a row)
            float s = 0.f;
#pragma unroll
            for (int c = 0; c < NC; ++c)
#pragma unroll
                for (int j = 0; j < 8; ++j) s += av[c][j];
            s += __shfl_xor(s, 16, 64); s += __shfl_xor(s, 32, 64);
            const float mu = s * (1.f / (float)TK);
            float vv = 0.f;
#pragma unroll
            for (int c = 0; c < NC; ++c)
#pragma unroll
                for (int j = 0; j < 8; ++j) { const float dd = av[c][j] - mu; vv += dd * dd; }
            vv += __shfl_xor(vv, 16, 64); vv += __shfl_xor(vv, 32, 64);
            const float rs = rsqrtf(vv * (1.f / (float)TK) + 1e-5f);
#pragma unroll
            for (int c = 0; c < NC; ++c) {
                const int kb = c * 32 + q * 8;
                const float4 g0 = *(const float4*)(lng + kb);
                const float4 g1 = *(const float4*)(lng + kb + 4);
                const float4 b0 = *(const float4*)(lnb + kb);
                const float4 b1 = *(const float4*)(lnb + kb + 4);
                const float gg[8] = {g0.x, g0.y, g0.z, g0.w, g1.x, g1.y, g1.z, g1.w};
                const float bbv[8] = {b0.x, b0.y, b0.z, b0.w, b1.x, b1.y, b1.z, b1.w};
#pragma unroll
                for (int j = 0; j < 8; ++j)
                    av[c][j] = (av[c][j] - mu) * rs * gg[j] + bbv[j];
            }
        }
#pragma unroll
        for (int c = 0; c < NC; ++c)
#pragma unroll
            for (int j = 0; j < 8; ++j) afr[c][j] = (short)f2bf(av[c][j]);
    }

    f32x4 acc[NT];
#pragma unroll
    for (int t = 0; t < NT; ++t) acc[t] = (f32x4){0.f, 0.f, 0.f, 0.f};

    __syncthreads();   // gl16 staging complete

    // ---- barrier-free MFMA loop ----
#pragma unroll
    for (int c = 0; c < NC; ++c)
#pragma unroll
        for (int t = 0; t < NT; ++t) {
            const bf16x8 bfr = *(const bf16x8*)&Bls[((t * NC + c) * 64 + l) * 8];
            acc[t] = __builtin_amdgcn_mfma_f32_16x16x32_bf16(afr[c], bfr, acc[t], 0, 0, 0);
        }

    // ---- epilogue: C/D layout col=lane&15, row=(lane>>4)*4+reg ----
    const int col0 = blockIdx.y * TBN;
    const int rb = blockIdx.x * 64 + w * 16 + q * 4;
#pragma unroll
    for (int t = 0; t < NT; ++t) {
        const int col = col0 + t * 16 + (l & 15);
        const float bv = BIAS ? bias[col] : 0.f;
#pragma unroll
        for (int rr = 0; rr < 4; ++rr) {
            const int row = rb + rr;
            if (row >= N) continue;
            float xv = acc[t][rr] + bv;
            if (ACC) xv += C32[(size_t)row * M + col];
            if (ACT == 1) xv = fmaxf(xv, 0.f);
            else if (ACT == 2) xv = 0.5f * xv * (1.f + erff(xv * 0.70710678118654752f));
            else if (ACT == 5) xv = (col < 128) ? tanhf(xv) : 1.f / (1.f + expf(-xv));
            if (W32) C32[(size_t)row * M + col] = xv;
            if (W16) C16[(size_t)row * M + col] = f2bf(xv);
        }
    }
}

// ------- GATv2: quarter-wave per edge, max-free softmax ---------------------
// X: [N][256] bf16 = [xl | xr]
__global__ __launch_bounds__(256) void gat3_k(const unsigned short* __restrict__ X,
                                              const float* __restrict__ att,
                                              const float* __restrict__ gbias,
                                              const int* __restrict__ rowptr,
                                              const int* __restrict__ esrc,
                                              float* __restrict__ H, int n) {
    const int l = threadIdx.x & 63;
    const int node = blockIdx.x * 4 + (threadIdx.x >> 6);
    if (node >= n) return;
    const int q = l >> 4;
    const int d0 = (l & 15) * 8;

    float a8[8], xr[8], xs[8];
    {
        const float4 t0 = *(const float4*)&att[d0];
        const float4 t1 = *(const float4*)&att[d0 + 4];
        a8[0] = t0.x; a8[1] = t0.y; a8[2] = t0.z; a8[3] = t0.w;
        a8[4] = t1.x; a8[5] = t1.y; a8[6] = t1.z; a8[7] = t1.w;
        const bf16x8 uxs = *(const bf16x8*)&X[(size_t)node * 256 + d0];
        const bf16x8 uxr = *(const bf16x8*)&X[(size_t)node * 256 + 128 + d0];
#pragma unroll
        for (int j = 0; j < 8; ++j) {
            xs[j] = bf2f((unsigned short)uxs[j]);
            xr[j] = bf2f((unsigned short)uxr[j]);
        }
    }

    float sc = 0.f;
#pragma unroll
    for (int j = 0; j < 8; ++j) {
        const float e = xs[j] + xr[j];
        sc = fmaf(a8[j], fmaxf(e, 0.2f * e), sc);
    }
#pragma unroll
    for (int m = 1; m < 16; m <<= 1) sc += __shfl_xor(sc, m, 64);
    const float wself = __expf(sc);
    float dsum = (q == 0) ? wself : 0.f;
    float acc[8];
#pragma unroll
    for (int j = 0; j < 8; ++j) acc[j] = (q == 0) ? wself * xs[j] : 0.f;

    const int p0 = rowptr[node], p1 = rowptr[node + 1];
    for (int p = p0 + q; p < p1; p += 4) {
        const int s = esrc[p];
        const bf16x8 ux = *(const bf16x8*)&X[(size_t)s * 256 + d0];
        float xl[8];
#pragma unroll
        for (int j = 0; j < 8; ++j) xl[j] = bf2f((unsigned short)ux[j]);
        float e_sc = 0.f;
#pragma unroll
        for (int j = 0; j < 8; ++j) {
            const float e = xl[j] + xr[j];
            e_sc = fmaf(a8[j], fmaxf(e, 0.2f * e), e_sc);
        }
#pragma unroll
        for (int m = 1; m < 16; m <<= 1) e_sc += __shfl_xor(e_sc, m, 64);
        const float wgt = __expf(e_sc);
        dsum += wgt;
#pragma unroll
        for (int j = 0; j < 8; ++j) acc[j] = fmaf(wgt, xl[j], acc[j]);
    }

#pragma unroll
    for (int m = 16; m < 64; m <<= 1) {
        dsum += __shfl_xor(dsum, m, 64);
#pragma unroll
        for (int j = 0; j < 8; ++j) acc[j] += __shfl_xor(acc[j], m, 64);
    }

    if (q == 0) {
        const float inv = 1.f / dsum;
        const size_t o = (size_t)node * D + d0;
        float4 h0 = *(const float4*)&H[o];
        float4 h1 = *(const float4*)&H[o + 4];
        float hv[8] = {h0.x, h0.y, h0.z, h0.w, h1.x, h1.y, h1.z, h1.w};
#pragma unroll
        for (int j = 0; j < 8; ++j) hv[j] += acc[j] * inv + gbias[d0 + j];
        *(float4*)&H[o]     = make_float4(hv[0], hv[1], hv[2], hv[3]);
        *(float4*)&H[o + 4] = make_float4(hv[4], hv[5], hv[6], hv[7]);
    }
}

// ---------------- pooling ----------------
// P: [N][256] f32 = [tanh(a) | sigmoid(b)]
__global__ __launch_bounds__(256) void poolA_k(const float* __restrict__ P,
                                               const float* __restrict__ Wc,
                                               const float* __restrict__ bc,
                                               float* __restrict__ A, int n) {
    const int lane = threadIdx.x & 63;
    const int node = blockIdx.x * 4 + (threadIdx.x >> 6);
    if (node >= n) return;
    const size_t o = (size_t)node * 256;
    const float v = wred_sum(P[o + lane] * P[o + 128 + lane] * Wc[lane] +
                             P[o + 64 + lane] * P[o + 192 + lane] * Wc[64 + lane]);
    if (lane == 0) A[node] = v + bc[0];
}

// max-free: |A| bounded (~sum|Wc| + bc), exp safe in fp32
__global__ __launch_bounds__(256) void wsum_k(const float* __restrict__ A,
                                              const float* __restrict__ H,
                                              float* __restrict__ red, int n) {
    const int lane = threadIdx.x & 63;
    const int gw = blockIdx.x * 4 + (threadIdx.x >> 6);
    const int nw = gridDim.x * 4;
    float a0 = 0.f, a1 = 0.f, dn = 0.f;
    for (int node = gw; node < n; node += nw) {
        const float w = __expf(A[node]);
        dn += w;
        a0 = fmaf(w, H[(size_t)node * D + lane], a0);
        a1 = fmaf(w, H[(size_t)node * D + 64 + lane], a1);
    }
    atomicAdd(&red[lane], a0);
    atomicAdd(&red[64 + lane], a1);
    if (lane == 0) atomicAdd(&red[128], dn);
}

__global__ __launch_bounds__(128) void final_k(const float* __restrict__ red,
                                               const float* __restrict__ rho_W,
                                               const float* __restrict__ rho_b,
                                               const float* __restrict__ cls_W,
                                               const float* __restrict__ cls_b,
                                               float* __restrict__ out) {
    __shared__ float hp[128];
    __shared__ float hr[128];
    __shared__ float lg[4];
    const int t = threadIdx.x;
    hp[t] = red[t] / red[128];
    __syncthreads();
    float s = rho_b[t];
    for (int k = 0; k < 128; ++k) s = fmaf(hp[k], rho_W[k * 128 + t], s);
    hr[t] = fmaxf(s, 0.f);
    __syncthreads();
    if (t < 4) {
        float l = cls_b[t];
        for (int k = 0; k < 128; ++k) l = fmaf(hr[k], cls_W[k * 4 + t], l);
        lg[t] = l;
    }
    __syncthreads();
    if (t == 0) {
        float hz[4], S[4];
        for (int c = 0; c < 4; ++c) hz[c] = 1.f / (1.f + expf(-lg[c]));
        S[0] = 1.f - hz[0];
        for (int c = 1; c < 4; ++c) S[c] = S[c - 1] * (1.f - hz[c]);
        int am = 0; float bm = lg[0];
        for (int c = 1; c < 4; ++c) if (lg[c] > bm) { bm = lg[c]; am = c; }
        out[0] = hz[0]; out[1] = hz[1]; out[2] = hz[2]; out[3] = hz[3];
        out[4] = S[0];  out[5] = S[1];  out[6] = S[2];  out[7] = S[3];
        out[8] = (float)am;
        out[9] = lg[0]; out[10] = lg[1]; out[11] = lg[2]; out[12] = lg[3];
    }
}

// ---------------------------------------------------------------------------
static inline int cdiv(int a, int b) { return (a + b - 1) / b; }

extern "C" void kernel_launch(void* const* d_in, const int* in_sizes, int n_in,
                              void* d_out, int out_size, void* d_ws, size_t ws_size,
                              hipStream_t stream) {
    const float* x      = (const float*)d_in[0];
    const int*   ei     = (const int*)d_in[1];
    const float* emb_W  = (const float*)d_in[2];
    const float* emb_b  = (const float*)d_in[3];
    const float* ln1_g  = (const float*)d_in[4];
    const float* ln1_b  = (const float*)d_in[5];
    const float* gat_Wl = (const float*)d_in[6];
    const float* gat_bl = (const float*)d_in[7];
    const float* gat_Wr = (const float*)d_in[8];
    const float* gat_br = (const float*)d_in[9];
    const float* gat_att  = (const float*)d_in[10];
    const float* gat_bias = (const float*)d_in[11];
    const float* mlp_w1[NBLK] = {(const float*)d_in[12], (const float*)d_in[14], (const float*)d_in[16]};
    const float* mlp_w2[NBLK] = {(const float*)d_in[13], (const float*)d_in[15], (const float*)d_in[17]};
    const float* attn_Wa = (const float*)d_in[18];
    const float* attn_ba = (const float*)d_in[19];
    const float* attn_Wb = (const float*)d_in[20];
    const float* attn_bb = (const float*)d_in[21];
    const float* attn_Wc = (const float*)d_in[22];
    const float* attn_bc = (const float*)d_in[23];
    const float* rho_W   = (const float*)d_in[24];
    const float* rho_b   = (const float*)d_in[25];
    const float* cls_W   = (const float*)d_in[26];
    const float* cls_b   = (const float*)d_in[27];
    float* out = (float*)d_out;

    const int N = in_sizes[0] / 512;   // 50000
    const int E = in_sizes[1] / 2;     // 800000
    const int* src = ei;
    const int* dst = ei + E;

    // ---- workspace layout ----
    char* base = (char*)d_ws;
    float* P = (float*)base;                                    // N*256 f32
    float* H = P + (size_t)N * 256;                             // N*128 f32
    unsigned short* X = (unsigned short*)(H + (size_t)N * D);   // N*256 bf16 [xl|xr]
    unsigned short* T = X + (size_t)N * 256;                    // N*384 bf16
    float* Avec = (float*)(T + (size_t)N * 384);                // N
    float* red  = Avec + N;                                     // 132
    float* sb   = red + 132;                                    // 4*256
    unsigned short* wbuf = (unsigned short*)(sb + 1024);        // 393216 bf16
    int* esrc   = (int*)(wbuf + 393216);                        // E
    int* deg    = esrc + E;                                     // N
    int* rowptr = deg + N;                                      // N+1
    int* fill   = rowptr + N + 1;                               // N
    int* bsum   = fill + N;                                     // 256

    // chunked weight sub-buffers
    unsigned short* embT = wbuf;                    // 2 x 32768 (K-split 256)
    unsigned short* gatT = wbuf + 65536;            // 3 x 32768 ([Wl|Wr] stacked)
    unsigned short* w1T0 = gatT + 3 * 32768;        // 16384
    unsigned short* w1T1 = w1T0 + 16384;            // 32768
    unsigned short* w1T2 = w1T1 + 32768;            // 49152
    unsigned short* w2T0 = w1T2 + 49152;            // 16384
    unsigned short* w2T1 = w2T0 + 16384;            // 32768
    unsigned short* w2T2 = w2T1 + 32768;            // 49152
    unsigned short* attT = w2T2 + 49152;            // 32768 ([Wa|Wb] stacked)
    unsigned short* w1T[NBLK] = {w1T0, w1T1, w1T2};
    unsigned short* w2T[NBLK] = {w2T0, w2T1, w2T2};

    // ---- CSR build ----
    const int nb = cdiv(N, 256);
    zero_k<<<cdiv(N, 256), 256, 0, stream>>>(deg, fill, red, N);
    hist_k<<<cdiv(E, 256), 256, 0, stream>>>(dst, deg, E);
    blockscan_k<<<nb, 256, 0, stream>>>(deg, rowptr, bsum, N);
    scansums_k<<<1, 256, 0, stream>>>(bsum, nb);
    addoff_k<<<nb, 256, 0, stream>>>(rowptr, bsum, N);
    scatter_k<<<cdiv(E, 256), 256, 0, stream>>>(src, dst, rowptr, fill, esrc, E);

    // ---- weight/bias prep ----
    {
        WPack p;
        p.w[0] = {emb_W,             embT,         256, 128};   // k 0..255
        p.w[1] = {emb_W + 256 * 128, embT + 32768, 256, 128};   // k 256..511
        for (int i = 0; i < 3; ++i) {
            p.w[2 + i] = {gat_Wl + (size_t)i * 16384, gatT + (size_t)i * 32768,         128, 128};
            p.w[5 + i] = {gat_Wr + (size_t)i * 16384, gatT + (size_t)i * 32768 + 16384, 128, 128};
            p.w[8 + i]  = {mlp_w1[i], w1T[i], 128, 128 * (i + 1)};
            p.w[11 + i] = {mlp_w2[i], w2T[i], 128 * (i + 1), 128};
        }
        p.w[14] = {attn_Wa, attT,         128, 128};
        p.w[15] = {attn_Wb, attT + 16384, 128, 128};
        wprep_k<<<dim3(64, 16), 256, 0, stream>>>(p);
    }
    bcat_k<<<1, 256, 0, stream>>>(gat_bl, gat_br, attn_ba, attn_bb, sb);

    const int gx = cdiv(N, 64);   // 782

    // ---- embedding: H = relu(x @ emb_W + emb_b), K split 2x256 ----
    rgemm_k<256, 128, 0, false, false, false, false, true, false>
        <<<dim3(gx, 1), 256, 0, stream>>>(x, embT, nullptr, nullptr, nullptr,
                                          H, nullptr, N, 512, 0, 128);
    rgemm_k<256, 128, 1, true, true, false, false, true, false>
        <<<dim3(gx, 1), 256, 0, stream>>>(x, embT + 32768, emb_b, nullptr, nullptr,
                                          H, nullptr, N, 512, 256, 128);

    // ---- 3 blocks ----
    for (int i = 0; i < NBLK; ++i) {
        // X = LN(H) @ [Wl|Wr] + [bl|br]   (LN fused)
        rgemm_k<128, 128, 0, true, false, true, false, false, true>
            <<<dim3(gx, 2), 256, 0, stream>>>(H, gatT + (size_t)i * 32768, sb + i * 256,
                                              ln1_g + i * D, ln1_b + i * D,
                                              nullptr, X, N, 128, 0, 256);
        gat3_k<<<cdiv(N, 4), 256, 0, stream>>>(X, gat_att + i * D, gat_bias + i * D,
                                               rowptr, esrc, H, N);
        const int h = D * (i + 1);
        // T = gelu(H @ w1)
        rgemm_k<128, 128, 2, false, false, false, false, false, true>
            <<<dim3(gx, i + 1), 256, 0, stream>>>(H, w1T[i], nullptr, nullptr, nullptr,
                                                  nullptr, T, N, 128, 0, h);
        // H += T @ w2
        if (i == 0)
            rgemm_k<128, 128, 0, false, true, false, true, true, false>
                <<<dim3(gx, 1), 256, 0, stream>>>(T, w2T[i], nullptr, nullptr, nullptr,
                                                  H, nullptr, N, h, 0, 128);
        else if (i == 1)
            rgemm_k<256, 128, 0, false, true, false, true, true, false>
                <<<dim3(gx, 1), 256, 0, stream>>>(T, w2T[i], nullptr, nullptr, nullptr,
                                                  H, nullptr, N, h, 0, 128);
        else
            rgemm_k<384, 64, 0, false, true, false, true, true, false>
                <<<dim3(gx, 2), 256, 0, stream>>>(T, w2T[i], nullptr, nullptr, nullptr,
                                                  H, nullptr, N, h, 0, 128);
    }

    // ---- gated attention pooling ----
    rgemm_k<128, 128, 5, true, false, false, false, true, false>
        <<<dim3(gx, 2), 256, 0, stream>>>(H, attT, sb + 3 * 256, nullptr, nullptr,
                                          P, nullptr, N, 128, 0, 256);
    poolA_k<<<cdiv(N, 4), 256, 0, stream>>>(P, attn_Wc, attn_bc, Avec, N);
    wsum_k<<<120, 256, 0, stream>>>(Avec, H, red, N);
    final_k<<<1, 128, 0, stream>>>(red, rho_W, rho_b, cls_W, cls_b, out);
}

// Round 5
// 748.228 us; speedup vs baseline: 2.3891x; 1.0317x over previous
//
#include <hip/hip_runtime.h>
#include <math.h>

// ---------------------------------------------------------------------------
// GraphMixer forward, round 5:
//   - rgemm_k: one dispatch per GEMM; in-kernel round loop (y-tiles or
//     k-rounds), TK=128/TBN=128, B pre-chunked per-round, A register-resident
//   - gat3_k: 2-deep data + 3-deep index software pipeline on edge gathers
//   - poolA+wsum fused (max-free softmax)
// ---------------------------------------------------------------------------

#define D 128
#define NBLK 3

typedef __attribute__((ext_vector_type(8))) short bf16x8;
typedef __attribute__((ext_vector_type(4))) float f32x4;

static __device__ __forceinline__ float wred_sum(float v) {
#pragma unroll
    for (int m = 1; m < 64; m <<= 1) v += __shfl_xor(v, m, 64);
    return v;
}

static __device__ __forceinline__ float bf2f(unsigned short u) {
    union { unsigned i; float f; } c; c.i = ((unsigned)u) << 16; return c.f;
}
static __device__ __forceinline__ unsigned short f2bf(float f) {
    union { float f; unsigned i; } c; c.f = f;
    unsigned r = c.i + 0x7fff + ((c.i >> 16) & 1);
    return (unsigned short)(r >> 16);
}

static __device__ __forceinline__ void gl16(const unsigned short* g, unsigned short* l) {
    __builtin_amdgcn_global_load_lds((const __attribute__((address_space(1))) void*)g,
                                     (__attribute__((address_space(3))) void*)l, 16, 0, 0);
}

// ---------------- CSR build ----------------
__global__ void zero_k(int* deg, int* fill, float* red, int n) {
    int i = blockIdx.x * blockDim.x + threadIdx.x;
    if (i < n) { deg[i] = 0; fill[i] = 0; }
    if (i < 132) red[i] = 0.f;
}

__global__ void hist_k(const int* __restrict__ dst, int* __restrict__ deg, int E) {
    int e = blockIdx.x * blockDim.x + threadIdx.x;
    if (e < E) atomicAdd(&deg[dst[e]], 1);
}

__global__ __launch_bounds__(256) void blockscan_k(const int* __restrict__ deg,
                                                   int* __restrict__ rowptr,
                                                   int* __restrict__ bsum, int n) {
    __shared__ int tmp[256];
    const int tid = threadIdx.x;
    const int i = blockIdx.x * 256 + tid;
    int v = (i < n) ? deg[i] : 0;
    tmp[tid] = v;
    __syncthreads();
#pragma unroll
    for (int off = 1; off < 256; off <<= 1) {
        int t = (tid >= off) ? tmp[tid - off] : 0;
        __syncthreads();
        tmp[tid] += t;
        __syncthreads();
    }
    if (i < n) rowptr[i + 1] = tmp[tid];
    if (tid == 255) bsum[blockIdx.x] = tmp[255];
}

__global__ __launch_bounds__(256) void scansums_k(int* __restrict__ bsum, int nb) {
    __shared__ int tmp[256];
    const int tid = threadIdx.x;
    int v = (tid < nb) ? bsum[tid] : 0;
    tmp[tid] = v;
    __syncthreads();
#pragma unroll
    for (int off = 1; off < 256; off <<= 1) {
        int t = (tid >= off) ? tmp[tid - off] : 0;
        __syncthreads();
        tmp[tid] += t;
        __syncthreads();
    }
    if (tid < nb) bsum[tid] = tmp[tid];
}

__global__ __launch_bounds__(256) void addoff_k(int* __restrict__ rowptr,
                                                const int* __restrict__ bsum, int n) {
    int i = blockIdx.x * 256 + threadIdx.x;
    if (i == 0) rowptr[0] = 0;
    if (i < n && blockIdx.x > 0) rowptr[i + 1] += bsum[blockIdx.x - 1];
}

__global__ void scatter_k(const int* __restrict__ src, const int* __restrict__ dst,
                          const int* __restrict__ rowptr, int* __restrict__ fill,
                          int* __restrict__ esrc, int E) {
    int e = blockIdx.x * blockDim.x + threadIdx.x;
    if (e < E) {
        int d = dst[e];
        int pos = rowptr[d] + atomicAdd(&fill[d], 1);
        esrc[pos] = src[e];
    }
}

// ---------------- weight prep: [K][M] f32 -> chunked bf16 fragment order ----
// chunk i = (t*(K/32)+c)*64+l ; elem j:
//   dst[i*8+j] = bf16(src[(c*32+(l>>4)*8+j)*M + t*16+(l&15)])
struct WDesc { const float* s; unsigned short* d; int K; int M; };
struct WPack { WDesc w[21]; };

__global__ __launch_bounds__(256) void wprep_k(WPack p) {
    WDesc d = p.w[blockIdx.y];
    const int nc = d.K / 32;
    const int chunks = (d.M / 16) * nc * 64;
    for (int i = blockIdx.x * 256 + threadIdx.x; i < chunks; i += gridDim.x * 256) {
        const int l = i & 63;
        const int c = (i >> 6) % nc;
        const int t = i / (64 * nc);
        const int m = t * 16 + (l & 15);
        const int kb = c * 32 + ((l >> 4) & 3) * 8;
#pragma unroll
        for (int j = 0; j < 8; ++j)
            d.d[(size_t)i * 8 + j] = f2bf(d.s[(size_t)(kb + j) * d.M + m]);
    }
}

// stacked biases: sb[i][256] = [bl_i | br_i] (i<3), sb[3][256] = [ba | bb]
__global__ __launch_bounds__(256) void bcat_k(const float* bl, const float* br,
                                              const float* ba, const float* bb,
                                              float* sb) {
    const int t = threadIdx.x;
    for (int i = 0; i < 3; ++i)
        sb[i * 256 + t] = (t < 128) ? bl[i * 128 + t] : br[i * 128 + t - 128];
    sb[3 * 256 + t] = (t < 128) ? ba[t] : bb[t - 128];
}

// ---------------- B-resident MFMA GEMM, in-kernel round loop ----------------
// TK=128 per round, TBN=128 per round. NR rounds:
//   KM=false: rounds advance output columns (col0 = rnd*128), acc reset/round
//   KM=true : rounds advance K (koff = rnd*128), acc persists, one epilogue
// B pre-chunked; round blob = 16384 elems (32 KB).
template <int NR, bool KM, int ACT, bool BIAS, bool ACC, bool LNM, bool A16,
          bool W32, bool W16>
__global__ __launch_bounds__(256) void rgemm_k(const void* __restrict__ Ap,
                                               const unsigned short* __restrict__ BTc,
                                               const float* __restrict__ bias,
                                               const float* __restrict__ lng,
                                               const float* __restrict__ lnb,
                                               float* __restrict__ C32,
                                               unsigned short* __restrict__ C16,
                                               int N, int strideA, int M) {
    __shared__ unsigned short Bls[128 * 128];   // 32 KB
    const int tid = threadIdx.x;
    const int w = tid >> 6, l = tid & 63;
    const int q = l >> 4;
    int r = blockIdx.x * 64 + w * 16 + (l & 15);
    if (r > N - 1) r = N - 1;

    bf16x8 afr[4];
    auto loadA = [&](int koff) {
        if (A16) {
            const unsigned short* A = (const unsigned short*)Ap;
#pragma unroll
            for (int c = 0; c < 4; ++c)
                afr[c] = *(const bf16x8*)(A + (size_t)r * strideA + koff + c * 32 + q * 8);
        } else {
            const float* A = (const float*)Ap;
            float av[4][8];
#pragma unroll
            for (int c = 0; c < 4; ++c) {
                const float* ap = A + (size_t)r * strideA + koff + c * 32 + q * 8;
                const float4 v0 = *(const float4*)ap;
                const float4 v1 = *(const float4*)(ap + 4);
                av[c][0] = v0.x; av[c][1] = v0.y; av[c][2] = v0.z; av[c][3] = v0.w;
                av[c][4] = v1.x; av[c][5] = v1.y; av[c][6] = v1.z; av[c][7] = v1.w;
            }
            if (LNM) {   // layernorm over the 128-dim row (lanes l^16,l^32,l^48)
                float s = 0.f;
#pragma unroll
                for (int c = 0; c < 4; ++c)
#pragma unroll
                    for (int j = 0; j < 8; ++j) s += av[c][j];
                s += __shfl_xor(s, 16, 64); s += __shfl_xor(s, 32, 64);
                const float mu = s * (1.f / 128.f);
                float vv = 0.f;
#pragma unroll
                for (int c = 0; c < 4; ++c)
#pragma unroll
                    for (int j = 0; j < 8; ++j) { const float dd = av[c][j] - mu; vv += dd * dd; }
                vv += __shfl_xor(vv, 16, 64); vv += __shfl_xor(vv, 32, 64);
                const float rs = rsqrtf(vv * (1.f / 128.f) + 1e-5f);
#pragma unroll
                for (int c = 0; c < 4; ++c) {
                    const int kb = c * 32 + q * 8;
                    const float4 g0 = *(const float4*)(lng + kb);
                    const float4 g1 = *(const float4*)(lng + kb + 4);
                    const float4 b0 = *(const float4*)(lnb + kb);
                    const float4 b1 = *(const float4*)(lnb + kb + 4);
                    const float gg[8] = {g0.x, g0.y, g0.z, g0.w, g1.x, g1.y, g1.z, g1.w};
                    const float bb[8] = {b0.x, b0.y, b0.z, b0.w, b1.x, b1.y, b1.z, b1.w};
#pragma unroll
                    for (int j = 0; j < 8; ++j)
                        av[c][j] = (av[c][j] - mu) * rs * gg[j] + bb[j];
                }
            }
#pragma unroll
            for (int c = 0; c < 4; ++c)
#pragma unroll
                for (int j = 0; j < 8; ++j) afr[c][j] = (short)f2bf(av[c][j]);
        }
    };

    f32x4 acc[8];
#pragma unroll
    for (int t = 0; t < 8; ++t) acc[t] = (f32x4){0.f, 0.f, 0.f, 0.f};

    if (!KM) loadA(0);

    const int rb = blockIdx.x * 64 + w * 16 + q * 4;
    auto epi = [&](int col0) {
#pragma unroll
        for (int t = 0; t < 8; ++t) {
            const int col = col0 + t * 16 + (l & 15);
            const float bv = BIAS ? bias[col] : 0.f;
#pragma unroll
            for (int rr = 0; rr < 4; ++rr) {
                const int row = rb + rr;
                if (row >= N) continue;
                float xv = acc[t][rr] + bv;
                if (ACC) xv += C32[(size_t)row * M + col];
                if (ACT == 1) xv = fmaxf(xv, 0.f);
                else if (ACT == 2) xv = 0.5f * xv * (1.f + erff(xv * 0.70710678118654752f));
                else if (ACT == 5) xv = (col < 128) ? tanhf(xv) : 1.f / (1.f + expf(-xv));
                if (W32) C32[(size_t)row * M + col] = xv;
                if (W16) C16[(size_t)row * M + col] = f2bf(xv);
            }
        }
    };

#pragma unroll
    for (int rnd = 0; rnd < NR; ++rnd) {
        if (rnd) __syncthreads();                       // prior Bls reads done
        const unsigned short* bsrc = BTc + (size_t)rnd * 16384;
#pragma unroll
        for (int i = 0; i < 8; ++i) {
            const int idx = i * 256 + tid;
            gl16(bsrc + (size_t)idx * 8, &Bls[idx * 8]);
        }
        if (KM) loadA(rnd * 128);
        __syncthreads();                                // staging complete
#pragma unroll
        for (int c = 0; c < 4; ++c)
#pragma unroll
            for (int t = 0; t < 8; ++t) {
                const bf16x8 bfr = *(const bf16x8*)&Bls[((t * 4 + c) * 64 + l) * 8];
                acc[t] = __builtin_amdgcn_mfma_f32_16x16x32_bf16(afr[c], bfr, acc[t], 0, 0, 0);
            }
        if (!KM) {
            epi(rnd * 128);
#pragma unroll
            for (int t = 0; t < 8; ++t) acc[t] = (f32x4){0.f, 0.f, 0.f, 0.f};
        }
    }
    if (KM) epi(0);
}

// ------- GATv2: quarter-wave per edge, max-free softmax, SW pipeline --------
// X: [N][256] bf16 = [xl | xr]
__global__ __launch_bounds__(256) void gat3_k(const unsigned short* __restrict__ X,
                                              const float* __restrict__ att,
                                              const float* __restrict__ gbias,
                                              const int* __restrict__ rowptr,
                                              const int* __restrict__ esrc,
                                              float* __restrict__ H, int n) {
    const int l = threadIdx.x & 63;
    const int node = blockIdx.x * 4 + (threadIdx.x >> 6);
    if (node >= n) return;
    const int q = l >> 4;
    const int d0 = (l & 15) * 8;

    float a8[8], xr[8], xs[8];
    {
        const float4 t0 = *(const float4*)&att[d0];
        const float4 t1 = *(const float4*)&att[d0 + 4];
        a8[0] = t0.x; a8[1] = t0.y; a8[2] = t0.z; a8[3] = t0.w;
        a8[4] = t1.x; a8[5] = t1.y; a8[6] = t1.z; a8[7] = t1.w;
        const bf16x8 uxs = *(const bf16x8*)&X[(size_t)node * 256 + d0];
        const bf16x8 uxr = *(const bf16x8*)&X[(size_t)node * 256 + 128 + d0];
#pragma unroll
        for (int j = 0; j < 8; ++j) {
            xs[j] = bf2f((unsigned short)uxs[j]);
            xr[j] = bf2f((unsigned short)uxr[j]);
        }
    }

    float sc = 0.f;
#pragma unroll
    for (int j = 0; j < 8; ++j) {
        const float e = xs[j] + xr[j];
        sc = fmaf(a8[j], fmaxf(e, 0.2f * e), sc);
    }
#pragma unroll
    for (int m = 1; m < 16; m <<= 1) sc += __shfl_xor(sc, m, 64);
    const float wself = __expf(sc);
    float dsum = (q == 0) ? wself : 0.f;
    float acc[8];
#pragma unroll
    for (int j = 0; j < 8; ++j) acc[j] = (q == 0) ? wself * xs[j] : 0.f;

    // pipelined edge loop: data 2 ahead, index 3 ahead
    const int p1 = rowptr[node + 1];
    int p = rowptr[node] + q;
    bool v0 = p < p1, v1 = p + 4 < p1, v2 = p + 8 < p1;
    int i2 = v2 ? esrc[p + 8] : 0;
    bf16x8 u0, u1;
    if (v0) u0 = *(const bf16x8*)&X[(size_t)esrc[p] * 256 + d0];
    if (v1) u1 = *(const bf16x8*)&X[(size_t)esrc[p + 4] * 256 + d0];
    while (v0) {
        bf16x8 u2;
        if (v2) u2 = *(const bf16x8*)&X[(size_t)i2 * 256 + d0];
        const bool v3 = p + 12 < p1;
        const int i3 = v3 ? esrc[p + 12] : 0;

        float xl[8];
#pragma unroll
        for (int j = 0; j < 8; ++j) xl[j] = bf2f((unsigned short)u0[j]);
        float e_sc = 0.f;
#pragma unroll
        for (int j = 0; j < 8; ++j) {
            const float e = xl[j] + xr[j];
            e_sc = fmaf(a8[j], fmaxf(e, 0.2f * e), e_sc);
        }
#pragma unroll
        for (int m = 1; m < 16; m <<= 1) e_sc += __shfl_xor(e_sc, m, 64);
        const float wgt = __expf(e_sc);
        dsum += wgt;
#pragma unroll
        for (int j = 0; j < 8; ++j) acc[j] = fmaf(wgt, xl[j], acc[j]);

        u0 = u1; u1 = u2; i2 = i3;
        v0 = v1; v1 = v2; v2 = v3;
        p += 4;
    }

#pragma unroll
    for (int m = 16; m < 64; m <<= 1) {
        dsum += __shfl_xor(dsum, m, 64);
#pragma unroll
        for (int j = 0; j < 8; ++j) acc[j] += __shfl_xor(acc[j], m, 64);
    }

    if (q == 0) {
        const float inv = 1.f / dsum;
        const size_t o = (size_t)node * D + d0;
        float4 h0 = *(const float4*)&H[o];
        float4 h1 = *(const float4*)&H[o + 4];
        float hv[8] = {h0.x, h0.y, h0.z, h0.w, h1.x, h1.y, h1.z, h1.w};
#pragma unroll
        for (int j = 0; j < 8; ++j) hv[j] += acc[j] * inv + gbias[d0 + j];
        *(float4*)&H[o]     = make_float4(hv[0], hv[1], hv[2], hv[3]);
        *(float4*)&H[o + 4] = make_float4(hv[4], hv[5], hv[6], hv[7]);
    }
}

// ---------------- fused pooling: score + exp + weighted sum -----------------
// P: [N][256] f32 = [tanh(a) | sigmoid(b)]; max-free (|A| bounded)
__global__ __launch_bounds__(256) void poolws_k(const float* __restrict__ P,
                                                const float* __restrict__ Wc,
                                                const float* __restrict__ bc,
                                                const float* __restrict__ H,
                                                float* __restrict__ red, int n) {
    const int lane = threadIdx.x & 63;
    const int gw = blockIdx.x * 4 + (threadIdx.x >> 6);
    const int nw = gridDim.x * 4;
    const float wc0 = Wc[lane], wc1 = Wc[64 + lane];
    const float bcv = bc[0];
    float a0 = 0.f, a1 = 0.f, dn = 0.f;
    for (int node = gw; node < n; node += nw) {
        const size_t o = (size_t)node * 256;
        const float v = wred_sum(P[o + lane] * P[o + 128 + lane] * wc0 +
                                 P[o + 64 + lane] * P[o + 192 + lane] * wc1);
        const float wgt = __expf(v + bcv);
        dn += wgt;
        a0 = fmaf(wgt, H[(size_t)node * D + lane], a0);
        a1 = fmaf(wgt, H[(size_t)node * D + 64 + lane], a1);
    }
    atomicAdd(&red[lane], a0);
    atomicAdd(&red[64 + lane], a1);
    if (lane == 0) atomicAdd(&red[128], dn);
}

__global__ __launch_bounds__(128) void final_k(const float* __restrict__ red,
                                               const float* __restrict__ rho_W,
                                               const float* __restrict__ rho_b,
                                               const float* __restrict__ cls_W,
                                               const float* __restrict__ cls_b,
                                               float* __restrict__ out) {
    __shared__ float hp[128];
    __shared__ float hr[128];
    __shared__ float lg[4];
    const int t = threadIdx.x;
    hp[t] = red[t] / red[128];
    __syncthreads();
    float s = rho_b[t];
    for (int k = 0; k < 128; ++k) s = fmaf(hp[k], rho_W[k * 128 + t], s);
    hr[t] = fmaxf(s, 0.f);
    __syncthreads();
    if (t < 4) {
        float l = cls_b[t];
        for (int k = 0; k < 128; ++k) l = fmaf(hr[k], cls_W[k * 4 + t], l);
        lg[t] = l;
    }
    __syncthreads();
    if (t == 0) {
        float hz[4], S[4];
        for (int c = 0; c < 4; ++c) hz[c] = 1.f / (1.f + expf(-lg[c]));
        S[0] = 1.f - hz[0];
        for (int c = 1; c < 4; ++c) S[c] = S[c - 1] * (1.f - hz[c]);
        int am = 0; float bm = lg[0];
        for (int c = 1; c < 4; ++c) if (lg[c] > bm) { bm = lg[c]; am = c; }
        out[0] = hz[0]; out[1] = hz[1]; out[2] = hz[2]; out[3] = hz[3];
        out[4] = S[0];  out[5] = S[1];  out[6] = S[2];  out[7] = S[3];
        out[8] = (float)am;
        out[9] = lg[0]; out[10] = lg[1]; out[11] = lg[2]; out[12] = lg[3];
    }
}

// ---------------------------------------------------------------------------
static inline int cdiv(int a, int b) { return (a + b - 1) / b; }

extern "C" void kernel_launch(void* const* d_in, const int* in_sizes, int n_in,
                              void* d_out, int out_size, void* d_ws, size_t ws_size,
                              hipStream_t stream) {
    const float* x      = (const float*)d_in[0];
    const int*   ei     = (const int*)d_in[1];
    const float* emb_W  = (const float*)d_in[2];
    const float* emb_b  = (const float*)d_in[3];
    const float* ln1_g  = (const float*)d_in[4];
    const float* ln1_b  = (const float*)d_in[5];
    const float* gat_Wl = (const float*)d_in[6];
    const float* gat_bl = (const float*)d_in[7];
    const float* gat_Wr = (const float*)d_in[8];
    const float* gat_br = (const float*)d_in[9];
    const float* gat_att  = (const float*)d_in[10];
    const float* gat_bias = (const float*)d_in[11];
    const float* mlp_w1[NBLK] = {(const float*)d_in[12], (const float*)d_in[14], (const float*)d_in[16]};
    const float* mlp_w2[NBLK] = {(const float*)d_in[13], (const float*)d_in[15], (const float*)d_in[17]};
    const float* attn_Wa = (const float*)d_in[18];
    const float* attn_ba = (const float*)d_in[19];
    const float* attn_Wb = (const float*)d_in[20];
    const float* attn_bb = (const float*)d_in[21];
    const float* attn_Wc = (const float*)d_in[22];
    const float* attn_bc = (const float*)d_in[23];
    const float* rho_W   = (const float*)d_in[24];
    const float* rho_b   = (const float*)d_in[25];
    const float* cls_W   = (const float*)d_in[26];
    const float* cls_b   = (const float*)d_in[27];
    float* out = (float*)d_out;

    const int N = in_sizes[0] / 512;   // 50000
    const int E = in_sizes[1] / 2;     // 800000
    const int* src = ei;
    const int* dst = ei + E;

    // ---- workspace layout ----
    char* base = (char*)d_ws;
    float* P = (float*)base;                                    // N*256 f32
    float* H = P + (size_t)N * 256;                             // N*128 f32
    unsigned short* X = (unsigned short*)(H + (size_t)N * D);   // N*256 bf16 [xl|xr]
    unsigned short* T = X + (size_t)N * 256;                    // N*384 bf16
    float* red  = (float*)(T + (size_t)N * 384);                // 132
    float* sb   = red + 132;                                    // 4*256
    unsigned short* wbuf = (unsigned short*)(sb + 1024);        // 393216 bf16
    int* esrc   = (int*)(wbuf + 393216);                        // E
    int* deg    = esrc + E;                                     // N
    int* rowptr = deg + N;                                      // N+1
    int* fill   = rowptr + N + 1;                               // N
    int* bsum   = fill + N;                                     // 256

    // chunked weight sub-buffers (per-round 16384-elem blobs, consecutive)
    unsigned short* embT = wbuf;                    // 4 rounds
    unsigned short* gatT = wbuf + 4 * 16384;        // 3 layers x 2 (Wl,Wr)
    unsigned short* w1T0 = gatT + 6 * 16384;        // 1 blob
    unsigned short* w1T1 = w1T0 + 16384;            // 2 blobs
    unsigned short* w1T2 = w1T1 + 2 * 16384;        // 3 blobs
    unsigned short* w2T0 = w1T2 + 3 * 16384;        // 1 blob
    unsigned short* w2T1 = w2T0 + 16384;            // 2 blobs
    unsigned short* w2T2 = w2T1 + 2 * 16384;        // 3 blobs
    unsigned short* attT = w2T2 + 3 * 16384;        // 2 blobs (Wa,Wb)
    unsigned short* w1T[NBLK] = {w1T0, w1T1, w1T2};
    unsigned short* w2T[NBLK] = {w2T0, w2T1, w2T2};

    // ---- CSR build ----
    const int nb = cdiv(N, 256);
    zero_k<<<cdiv(N, 256), 256, 0, stream>>>(deg, fill, red, N);
    hist_k<<<cdiv(E, 256), 256, 0, stream>>>(dst, deg, E);
    blockscan_k<<<nb, 256, 0, stream>>>(deg, rowptr, bsum, N);
    scansums_k<<<1, 256, 0, stream>>>(bsum, nb);
    addoff_k<<<nb, 256, 0, stream>>>(rowptr, bsum, N);
    scatter_k<<<cdiv(E, 256), 256, 0, stream>>>(src, dst, rowptr, fill, esrc, E);

    // ---- weight/bias prep (21 descs, all K=128 per-round blobs) ----
    {
        WPack p;
        int di = 0;
        for (int r = 0; r < 4; ++r)
            p.w[di++] = {emb_W + (size_t)r * 128 * 128, embT + (size_t)r * 16384, 128, 128};
        for (int i = 0; i < 3; ++i) {
            p.w[di++] = {gat_Wl + (size_t)i * 16384, gatT + (size_t)(2 * i) * 16384, 128, 128};
            p.w[di++] = {gat_Wr + (size_t)i * 16384, gatT + (size_t)(2 * i + 1) * 16384, 128, 128};
        }
        for (int i = 0; i < 3; ++i)
            p.w[di++] = {mlp_w1[i], w1T[i], 128, 128 * (i + 1)};
        for (int i = 0; i < 3; ++i)
            for (int r = 0; r <= i; ++r)
                p.w[di++] = {mlp_w2[i] + (size_t)r * 128 * 128, w2T[i] + (size_t)r * 16384, 128, 128};
        p.w[di++] = {attn_Wa, attT, 128, 128};
        p.w[di++] = {attn_Wb, attT + 16384, 128, 128};
        wprep_k<<<dim3(32, 21), 256, 0, stream>>>(p);
    }
    bcat_k<<<1, 256, 0, stream>>>(gat_bl, gat_br, attn_ba, attn_bb, sb);

    const int gx = cdiv(N, 64);   // 782

    // ---- embedding: H = relu(x @ emb_W + emb_b), 4 k-rounds in-kernel ----
    rgemm_k<4, true, 1, true, false, false, false, true, false>
        <<<gx, 256, 0, stream>>>(x, embT, emb_b, nullptr, nullptr,
                                 H, nullptr, N, 512, 128);

    // ---- 3 blocks ----
    for (int i = 0; i < NBLK; ++i) {
        // X = LN(H) @ [Wl|Wr] + [bl|br]  (2 col-rounds, LN fused)
        rgemm_k<2, false, 0, true, false, true, false, false, true>
            <<<gx, 256, 0, stream>>>(H, gatT + (size_t)(2 * i) * 16384, sb + i * 256,
                                     ln1_g + i * D, ln1_b + i * D, nullptr, X, N, 128, 256);
        gat3_k<<<cdiv(N, 4), 256, 0, stream>>>(X, gat_att + i * D, gat_bias + i * D,
                                               rowptr, esrc, H, N);
        const int h = D * (i + 1);
        // T = gelu(H @ w1)  (i+1 col-rounds)
        if (i == 0)
            rgemm_k<1, false, 2, false, false, false, false, false, true>
                <<<gx, 256, 0, stream>>>(H, w1T[i], nullptr, nullptr, nullptr,
                                         nullptr, T, N, 128, h);
        else if (i == 1)
            rgemm_k<2, false, 2, false, false, false, false, false, true>
                <<<gx, 256, 0, stream>>>(H, w1T[i], nullptr, nullptr, nullptr,
                                         nullptr, T, N, 128, h);
        else
            rgemm_k<3, false, 2, false, false, false, false, false, true>
                <<<gx, 256, 0, stream>>>(H, w1T[i], nullptr, nullptr, nullptr,
                                         nullptr, T, N, 128, h);
        // H += T @ w2  (i+1 k-rounds)
        if (i == 0)
            rgemm_k<1, true, 0, false, true, false, true, true, false>
                <<<gx, 256, 0, stream>>>(T, w2T[i], nullptr, nullptr, nullptr,
                                         H, nullptr, N, h, 128);
        else if (i == 1)
            rgemm_k<2, true, 0, false, true, false, true, true, false>
                <<<gx, 256, 0, stream>>>(T, w2T[i], nullptr, nullptr, nullptr,
                                         H, nullptr, N, h, 128);
        else
            rgemm_k<3, true, 0, false, true, false, true, true, false>
                <<<gx, 256, 0, stream>>>(T, w2T[i], nullptr, nullptr, nullptr,
                                         H, nullptr, N, h, 128);
    }

    // ---- gated attention pooling ----
    rgemm_k<2, false, 5, true, false, false, false, true, false>
        <<<gx, 256, 0, stream>>>(H, attT, sb + 3 * 256, nullptr, nullptr,
                                 P, nullptr, N, 128, 256);
    poolws_k<<<120, 256, 0, stream>>>(P, attn_Wc, attn_bc, H, red, N);
    final_k<<<1, 128, 0, stream>>>(red, rho_W, rho_b, cls_W, cls_b, out);
}